// Round 1
// baseline (4800.511 us; speedup 1.0000x reference)
//
#include <hip/hip_runtime.h>
#include <math.h>

// ---------------------------------------------------------------------------
// Model dims (fixed by the reference)
// ---------------------------------------------------------------------------
#define BATCH   1024
#define NPG     32
#define NNODES  (BATCH * NPG)      // 32768
#define EPG     128
#define NEDGE   (BATCH * EPG)      // 131072
#define INFEAT  78
#define CCH     128
#define NHEAD   8
#define GENE    18000
#define PROT    6688
#define FPD     2048

#define ACT_NONE 0
#define ACT_RELU 1
#define ACT_ELU  2

// ---------------------------------------------------------------------------
// Generic fp32 GEMM:  C[M,N] = act(rowscale[m] * (A[M,K] @ W[K,N]) + bias[n])
// BM=BN=64, BK=16, 256 threads, 4x4 micro-tile.
// ---------------------------------------------------------------------------
#define BM 64
#define BN 64
#define BK 16

__global__ __launch_bounds__(256) void gemm_f32_kernel(
    const float* __restrict__ A, const float* __restrict__ W,
    const float* __restrict__ bias, const float* __restrict__ rowscale,
    float* __restrict__ C, int M, int N, int K, int act)
{
    __shared__ float As[BK][BM];
    __shared__ float Bs[BK][BN];

    const int tid = threadIdx.x;
    const int tm  = tid >> 4;          // 0..15 (row group)
    const int tn  = tid & 15;          // 0..15 (col group)
    const int row0 = blockIdx.y * BM;
    const int col0 = blockIdx.x * BN;

    const int a_m = tid >> 2;          // 0..63
    const int a_k = (tid & 3) * 4;     // 0,4,8,12
    const int b_k = tid >> 4;          // 0..15
    const int b_n = (tid & 15) * 4;    // 0..60

    float acc[4][4] = {};
    const bool k_vec_ok = ((K & 3) == 0);

    for (int k0 = 0; k0 < K; k0 += BK) {
        // ---- load A tile (transposed into LDS) ----
        {
            int gm = row0 + a_m;
            float4 v = make_float4(0.f, 0.f, 0.f, 0.f);
            if (gm < M) {
                const float* ap = A + (long)gm * K + k0 + a_k;
                if (k_vec_ok && (k0 + a_k + 3 < K)) {
                    v = *(const float4*)ap;
                } else {
                    float t0 = 0.f, t1 = 0.f, t2 = 0.f, t3 = 0.f;
                    if (k0 + a_k + 0 < K) t0 = ap[0];
                    if (k0 + a_k + 1 < K) t1 = ap[1];
                    if (k0 + a_k + 2 < K) t2 = ap[2];
                    if (k0 + a_k + 3 < K) t3 = ap[3];
                    v = make_float4(t0, t1, t2, t3);
                }
            }
            As[a_k + 0][a_m] = v.x;
            As[a_k + 1][a_m] = v.y;
            As[a_k + 2][a_m] = v.z;
            As[a_k + 3][a_m] = v.w;
        }
        // ---- load B tile ----
        {
            int gk = k0 + b_k;
            float4 v = make_float4(0.f, 0.f, 0.f, 0.f);
            if (gk < K) {
                const float* wp = W + (long)gk * N + col0 + b_n;
                if (col0 + b_n + 3 < N) {
                    v = *(const float4*)wp;
                } else {
                    float t0 = 0.f, t1 = 0.f, t2 = 0.f, t3 = 0.f;
                    if (col0 + b_n + 0 < N) t0 = wp[0];
                    if (col0 + b_n + 1 < N) t1 = wp[1];
                    if (col0 + b_n + 2 < N) t2 = wp[2];
                    if (col0 + b_n + 3 < N) t3 = wp[3];
                    v = make_float4(t0, t1, t2, t3);
                }
            }
            *(float4*)&Bs[b_k][b_n] = v;
        }
        __syncthreads();

        #pragma unroll
        for (int kk = 0; kk < BK; kk++) {
            float ar[4], br[4];
            *(float4*)ar = *(const float4*)&As[kk][tm * 4];
            *(float4*)br = *(const float4*)&Bs[kk][tn * 4];
            #pragma unroll
            for (int i = 0; i < 4; i++)
                #pragma unroll
                for (int j = 0; j < 4; j++)
                    acc[i][j] += ar[i] * br[j];
        }
        __syncthreads();
    }

    #pragma unroll
    for (int i = 0; i < 4; i++) {
        int gm = row0 + tm * 4 + i;
        if (gm >= M) continue;
        float rs = rowscale ? rowscale[gm] : 1.0f;
        #pragma unroll
        for (int j = 0; j < 4; j++) {
            int gn = col0 + tn * 4 + j;
            if (gn >= N) continue;
            float v = acc[i][j] * rs + (bias ? bias[gn] : 0.0f);
            if (act == ACT_RELU)      v = fmaxf(v, 0.0f);
            else if (act == ACT_ELU)  v = (v > 0.0f) ? v : (expf(v) - 1.0f);
            C[(long)gm * N + gn] = v;
        }
    }
}

// ---------------------------------------------------------------------------
// Attention source/dest logits: a_s[n,h] = sum_c h[n,h,c]*a_src[h,c] (C==128)
// One wave per (node, head); 4 waves per block.
// ---------------------------------------------------------------------------
__global__ __launch_bounds__(256) void attn_dot_kernel(
    const float* __restrict__ h, const float* __restrict__ a_src,
    const float* __restrict__ a_dst, float* __restrict__ s_out,
    float* __restrict__ d_out, int n_nodes, int H)
{
    const int wave = threadIdx.x >> 6;
    const int lane = threadIdx.x & 63;
    const long pair = (long)blockIdx.x * 4 + wave;
    if (pair >= (long)n_nodes * H) return;
    const int n  = (int)(pair / H);
    const int hd = (int)(pair % H);

    const float* hp = h + (long)n * H * CCH + hd * CCH;
    const float* as = a_src + hd * CCH;
    const float* ad = a_dst + hd * CCH;
    float v0 = hp[lane], v1 = hp[lane + 64];
    float s = v0 * as[lane] + v1 * as[lane + 64];
    float d = v0 * ad[lane] + v1 * ad[lane + 64];
    #pragma unroll
    for (int o = 32; o > 0; o >>= 1) {
        s += __shfl_xor(s, o, 64);
        d += __shfl_xor(d, o, 64);
    }
    if (lane == 0) { s_out[pair] = s; d_out[pair] = d; }
}

// monotone float<->uint encoding for atomicMax on floats
__device__ __forceinline__ unsigned enc_f(float f) {
    unsigned u = __float_as_uint(f);
    return (u >> 31) ? ~u : (u | 0x80000000u);
}
__device__ __forceinline__ float dec_f(unsigned e) {
    return (e >> 31) ? __uint_as_float(e ^ 0x80000000u) : __uint_as_float(~e);
}

// ---------------------------------------------------------------------------
// Fused GAT softmax + aggregation, one block per (graph, head).
// Edges of graph g are edge ids [g*EPG, (g+1)*EPG); all endpoints inside the
// graph's 32-node window; 32 self-loops appended logically (slots 128..159).
// out[n, hd*128+c] = elu( sum_e alpha_e * h[src_e, hd*128+c] + bias )
// ---------------------------------------------------------------------------
__global__ __launch_bounds__(128) void gat_agg_kernel(
    const float* __restrict__ h, const float* __restrict__ a_s,
    const float* __restrict__ a_d, const int* __restrict__ esrc,
    const int* __restrict__ edst, const float* __restrict__ bias,
    float* __restrict__ out, int H)
{
    const int g   = blockIdx.x / H;
    const int hd  = blockIdx.x % H;
    const int tid = threadIdx.x;            // 128 threads
    const int base = g * NPG;
    const int HC = H * CCH;

    __shared__ float h_l[NPG][CCH];
    __shared__ float o_l[NPG][CCH];
    __shared__ float as_l[NPG], ad_l[NPG];
    __shared__ unsigned m_l[NPG];
    __shared__ float den_l[NPG];
    __shared__ float sc_l[EPG + NPG];
    __shared__ unsigned char s_l[EPG + NPG], d_l[EPG + NPG];

    for (int r = 0; r < NPG; r++) {
        h_l[r][tid] = h[(long)(base + r) * HC + hd * CCH + tid];
        o_l[r][tid] = 0.0f;
    }
    if (tid < NPG) {
        as_l[tid]  = a_s[(base + tid) * H + hd];
        ad_l[tid]  = a_d[(base + tid) * H + hd];
        m_l[tid]   = 0u;
        den_l[tid] = 0.0f;
    }
    __syncthreads();

    // scores + segment max
    for (int j = tid; j < EPG + NPG; j += 128) {
        int s, d;
        if (j < EPG) {
            s = esrc[g * EPG + j] - base;
            d = edst[g * EPG + j] - base;
        } else {
            s = d = j - EPG;
        }
        float e = as_l[s] + ad_l[d];
        e = (e >= 0.0f) ? e : 0.2f * e;        // leaky_relu 0.2
        sc_l[j] = e;
        s_l[j] = (unsigned char)s;
        d_l[j] = (unsigned char)d;
        atomicMax(&m_l[d], enc_f(e));
    }
    __syncthreads();

    // exp + segment sum
    for (int j = tid; j < EPG + NPG; j += 128) {
        float ex = expf(sc_l[j] - dec_f(m_l[d_l[j]]));
        sc_l[j] = ex;
        atomicAdd(&den_l[d_l[j]], ex);
    }
    __syncthreads();

    // normalize
    for (int j = tid; j < EPG + NPG; j += 128)
        sc_l[j] = sc_l[j] / (den_l[d_l[j]] + 1e-16f);
    __syncthreads();

    // aggregate: serial edge loop, each thread owns feature column `tid`
    for (int j = 0; j < EPG + NPG; j++) {
        int s = s_l[j], d = d_l[j];
        float al = sc_l[j];
        o_l[d][tid] += al * h_l[s][tid];
    }

    // epilogue: + bias, elu
    float b = bias[hd * CCH + tid];
    for (int r = 0; r < NPG; r++) {
        float v = o_l[r][tid] + b;
        v = (v > 0.0f) ? v : (expf(v) - 1.0f);
        out[(long)(base + r) * HC + hd * CCH + tid] = v;
    }
}

// ---------------------------------------------------------------------------
// Global max pool over each graph's 32 nodes (feature dim 128)
// ---------------------------------------------------------------------------
__global__ __launch_bounds__(128) void maxpool_kernel(
    const float* __restrict__ x, float* __restrict__ out)
{
    const int g = blockIdx.x;
    const int c = threadIdx.x;
    float m = -INFINITY;
    for (int r = 0; r < NPG; r++)
        m = fmaxf(m, x[(long)(g * NPG + r) * CCH + c]);
    out[g * CCH + c] = m;
}

// ---------------------------------------------------------------------------
// Per-row inverse L2 norm (gene branch)
// ---------------------------------------------------------------------------
__global__ __launch_bounds__(256) void rownorm_kernel(
    const float* __restrict__ x, float* __restrict__ inv, int K)
{
    const int row = blockIdx.x;
    const int tid = threadIdx.x;
    const float* xp = x + (long)row * K;
    float s = 0.f;
    for (int k = tid; k < K; k += 256) { float v = xp[k]; s += v * v; }
    __shared__ float red[256];
    red[tid] = s;
    __syncthreads();
    for (int o = 128; o > 0; o >>= 1) {
        if (tid < o) red[tid] += red[tid + o];
        __syncthreads();
    }
    if (tid == 0) inv[row] = 1.0f / fmaxf(sqrtf(red[0]), 1e-12f);
}

// ---------------------------------------------------------------------------
// Copy a rows x cols block into dst with leading dim dstLD at column dstOff
// ---------------------------------------------------------------------------
__global__ __launch_bounds__(256) void copycols_kernel(
    float* __restrict__ dst, int dstLD, int dstOff,
    const float* __restrict__ src, int rows, int cols)
{
    long idx = (long)blockIdx.x * 256 + threadIdx.x;
    long total = (long)rows * cols;
    if (idx >= total) return;
    int r = (int)(idx / cols);
    int c = (int)(idx % cols);
    dst[(long)r * dstLD + dstOff + c] = src[idx];
}

// ---------------------------------------------------------------------------
// Final N_TASKS=1 output: out[b] = y[b,:256] . w + bout
// ---------------------------------------------------------------------------
__global__ __launch_bounds__(256) void final_kernel(
    const float* __restrict__ y, const float* __restrict__ w,
    const float* __restrict__ b, float* __restrict__ out)
{
    const int row = blockIdx.x;
    const int tid = threadIdx.x;
    float v = y[(long)row * 256 + tid] * w[tid];
    __shared__ float red[256];
    red[tid] = v;
    __syncthreads();
    for (int o = 128; o > 0; o >>= 1) {
        if (tid < o) red[tid] += red[tid + o];
        __syncthreads();
    }
    if (tid == 0) out[row] = red[0] + b[0];
}

// ---------------------------------------------------------------------------
// Host side
// ---------------------------------------------------------------------------
static inline void launch_gemm(const float* A, const float* W, const float* bias,
                               const float* rowscale, float* C,
                               int M, int N, int K, int act, hipStream_t stream)
{
    dim3 grid((N + BN - 1) / BN, (M + BM - 1) / BM);
    gemm_f32_kernel<<<grid, 256, 0, stream>>>(A, W, bias, rowscale, C, M, N, K, act);
}

extern "C" void kernel_launch(void* const* d_in, const int* in_sizes, int n_in,
                              void* d_out, int out_size, void* d_ws, size_t ws_size,
                              hipStream_t stream)
{
    const float* x1      = (const float*)d_in[0];
    const float* x2      = (const float*)d_in[1];
    const float* gene    = (const float*)d_in[2];
    const float* drr     = (const float*)d_in[3];
    const float* drc     = (const float*)d_in[4];
    const float* prot    = (const float*)d_in[5];
    const int*   ei1     = (const int*)d_in[6];
    const int*   ei2     = (const int*)d_in[7];
    // d_in[8] = batch (implicit from layout; unused)
    const float* W_gat1  = (const float*)d_in[9];
    const float* b_gat1  = (const float*)d_in[10];
    const float* a_src1  = (const float*)d_in[11];
    const float* a_dst1  = (const float*)d_in[12];
    const float* W_gat2  = (const float*)d_in[13];
    const float* b_gat2  = (const float*)d_in[14];
    const float* a_src2  = (const float*)d_in[15];
    const float* a_dst2  = (const float*)d_in[16];
    const float* W_fcg   = (const float*)d_in[17];
    const float* b_fcg   = (const float*)d_in[18];
    const float* Wr1     = (const float*)d_in[19];
    const float* br1     = (const float*)d_in[20];
    const float* Wr2     = (const float*)d_in[21];
    const float* br2     = (const float*)d_in[22];
    const float* Wr3     = (const float*)d_in[23];
    const float* br3     = (const float*)d_in[24];
    const float* Wp1     = (const float*)d_in[25];
    const float* bp1     = (const float*)d_in[26];
    const float* Wp2     = (const float*)d_in[27];
    const float* bp2     = (const float*)d_in[28];
    const float* Wp3     = (const float*)d_in[29];
    const float* bp3     = (const float*)d_in[30];
    const float* Wdrr    = (const float*)d_in[31];
    const float* bdrr    = (const float*)d_in[32];
    const float* Wdrc    = (const float*)d_in[33];
    const float* bdrc    = (const float*)d_in[34];
    const float* Wf1     = (const float*)d_in[35];
    const float* bf1     = (const float*)d_in[36];
    const float* Wf2     = (const float*)d_in[37];
    const float* bf2     = (const float*)d_in[38];
    const float* Wout    = (const float*)d_in[39];
    const float* bout    = (const float*)d_in[40];
    float* outp = (float*)d_out;

    char* ws = (char*)d_ws;
    // big regions
    float* bufA   = (float*)(ws + 0);                       // 134,217,728 B
    float* bufB   = (float*)(ws + 134217728L);              // 134,217,728 B
    float* bufH2  = (float*)(ws + 268435456L);              //  16,777,216 B
    float* bufO2  = (float*)(ws + 285212672L);              //  16,777,216 B
    // small persistent region
    float* asrcb  = (float*)(ws + 301989888L);              // 1,048,576
    float* adstb  = (float*)(ws + 303038464L);              // 1,048,576
    float* as2b   = (float*)(ws + 304087040L);              //   131,072
    float* ad2b   = (float*)(ws + 304218112L);              //   131,072
    float* pooled = (float*)(ws + 304349184L);              //   524,288
    float* g1     = (float*)(ws + 304873472L);              //   524,288
    float* g2     = (float*)(ws + 305397760L);              //   524,288
    float* invn   = (float*)(ws + 305922048L);              //     4,096
    // MLP-phase aliases inside bufA (drug branches done by then)
    float* cell1  = (float*)((char*)bufA + 0);              // 1024x2048
    float* p1     = (float*)((char*)bufA + 16777216L);      // 1024x1024
    float* cell2  = (float*)((char*)bufA + 33554432L);      // 1024x512
    float* p2     = (float*)((char*)bufA + 41943040L);      // 1024x512
    float* cat1   = (float*)((char*)bufA + 50331648L);      // 1024x2176
    float* cat2   = (float*)((char*)bufA + 67108864L);      // 1024x2176
    float* ybuf   = (float*)((char*)bufA + 83886080L);      // 1024x4864
    float* y1     = (float*)((char*)bufA + 104857600L);     // 1024x512
    float* y2     = (float*)((char*)bufA + 113246208L);     // 1024x256
    // aliases inside bufB
    float* d1     = (float*)((char*)bufB + 0);              // 1024x2176
    float* d2     = (float*)((char*)bufB + 16777216L);      // 1024x2176
    float* cvec   = (float*)((char*)bufB + 33554432L);      // 1024x256
    float* pvec   = (float*)((char*)bufB + 41943040L);      // 1024x256

    const int E = in_sizes[6] / 2;   // 131072

    // ---------------- drug branches ----------------
    for (int drug = 0; drug < 2; drug++) {
        const float* x  = drug ? x2 : x1;
        const int*   es = (drug ? ei2 : ei1);
        const int*   ed = es + E;
        float*       gv = drug ? g2 : g1;

        // GAT1: h = x @ W1   (bias applied post-aggregation)
        launch_gemm(x, W_gat1, nullptr, nullptr, bufA, NNODES, NHEAD * CCH, INFEAT, ACT_NONE, stream);
        attn_dot_kernel<<<NNODES * NHEAD / 4, 256, 0, stream>>>(bufA, a_src1, a_dst1, asrcb, adstb, NNODES, NHEAD);
        gat_agg_kernel<<<BATCH * NHEAD, 128, 0, stream>>>(bufA, asrcb, adstb, es, ed, b_gat1, bufB, NHEAD);

        // GAT2: h2 = out1 @ W2
        launch_gemm(bufB, W_gat2, nullptr, nullptr, bufH2, NNODES, CCH, NHEAD * CCH, ACT_NONE, stream);
        attn_dot_kernel<<<NNODES / 4, 256, 0, stream>>>(bufH2, a_src2, a_dst2, as2b, ad2b, NNODES, 1);
        gat_agg_kernel<<<BATCH, 128, 0, stream>>>(bufH2, as2b, ad2b, es, ed, b_gat2, bufO2, 1);

        // pool + fcg
        maxpool_kernel<<<BATCH, 128, 0, stream>>>(bufO2, pooled);
        launch_gemm(pooled, W_fcg, b_fcg, nullptr, gv, BATCH, CCH, CCH, ACT_RELU, stream);
    }

    // ---------------- gene branch ----------------
    rownorm_kernel<<<BATCH, 256, 0, stream>>>(gene, invn, GENE);
    launch_gemm(gene,  Wr1, br1, invn,    cell1, BATCH, 2048, GENE, ACT_RELU, stream);
    launch_gemm(cell1, Wr2, br2, nullptr, cell2, BATCH, 512, 2048, ACT_RELU, stream);
    launch_gemm(cell2, Wr3, br3, nullptr, cvec,  BATCH, 256, 512,  ACT_RELU, stream);

    // ---------------- protein branch ----------------
    launch_gemm(prot, Wp1, bp1, nullptr, p1,   BATCH, 1024, PROT, ACT_ELU, stream);
    launch_gemm(p1,   Wp2, bp2, nullptr, p2,   BATCH, 512, 1024,  ACT_ELU, stream);
    launch_gemm(p2,   Wp3, bp3, nullptr, pvec, BATCH, 256, 512,   ACT_RELU, stream);

    // ---------------- fingerprint fusion ----------------
    {
        long n;
        n = (long)BATCH * CCH;
        copycols_kernel<<<(int)((n + 255) / 256), 256, 0, stream>>>(cat1, CCH + FPD, 0,   g1,  BATCH, CCH);
        n = (long)BATCH * FPD;
        copycols_kernel<<<(int)((n + 255) / 256), 256, 0, stream>>>(cat1, CCH + FPD, CCH, drr, BATCH, FPD);
        n = (long)BATCH * CCH;
        copycols_kernel<<<(int)((n + 255) / 256), 256, 0, stream>>>(cat2, CCH + FPD, 0,   g2,  BATCH, CCH);
        n = (long)BATCH * FPD;
        copycols_kernel<<<(int)((n + 255) / 256), 256, 0, stream>>>(cat2, CCH + FPD, CCH, drc, BATCH, FPD);
    }
    launch_gemm(cat1, Wdrr, bdrr, nullptr, d1, BATCH, CCH + FPD, CCH + FPD, ACT_RELU, stream);
    launch_gemm(cat2, Wdrc, bdrc, nullptr, d2, BATCH, CCH + FPD, CCH + FPD, ACT_RELU, stream);

    // ---------------- concat + predictor ----------------
    {
        const int YD = 2 * (CCH + FPD) + 256 + 256;   // 4864
        long n;
        n = (long)BATCH * (CCH + FPD);
        copycols_kernel<<<(int)((n + 255) / 256), 256, 0, stream>>>(ybuf, YD, 0,              d1,   BATCH, CCH + FPD);
        copycols_kernel<<<(int)((n + 255) / 256), 256, 0, stream>>>(ybuf, YD, CCH + FPD,      d2,   BATCH, CCH + FPD);
        n = (long)BATCH * 256;
        copycols_kernel<<<(int)((n + 255) / 256), 256, 0, stream>>>(ybuf, YD, 2 * (CCH + FPD),       cvec, BATCH, 256);
        copycols_kernel<<<(int)((n + 255) / 256), 256, 0, stream>>>(ybuf, YD, 2 * (CCH + FPD) + 256, pvec, BATCH, 256);
    }
    launch_gemm(ybuf, Wf1, bf1, nullptr, y1, BATCH, 512, 4864, ACT_RELU, stream);
    launch_gemm(y1,   Wf2, bf2, nullptr, y2, BATCH, 256, 512,  ACT_RELU, stream);
    final_kernel<<<BATCH, 256, 0, stream>>>(y2, Wout, bout, outp);
}

// Round 2
// 2345.659 us; speedup vs baseline: 2.0466x; 2.0466x over previous
//
#include <hip/hip_runtime.h>
#include <math.h>

// ---------------------------------------------------------------------------
// Model dims (fixed by the reference)
// ---------------------------------------------------------------------------
#define BATCH   1024
#define NPG     32
#define NNODES  (BATCH * NPG)      // 32768
#define EPG     128
#define INFEAT  78
#define CCH     128
#define NHEAD   8
#define GENE    18000
#define GENEP   18016              // padded to %32
#define PROT    6688
#define FPD     2048

#define ACT_NONE 0
#define ACT_RELU 1
#define ACT_ELU  2

typedef unsigned short ushort_t;
typedef __bf16 bf16x8_t __attribute__((ext_vector_type(8)));
typedef float  f32x4_t  __attribute__((ext_vector_type(4)));

__device__ __forceinline__ float b2f(ushort_t u) {
    return __uint_as_float(((unsigned)u) << 16);
}
__device__ __forceinline__ ushort_t f2b(float f) {
    unsigned x = __float_as_uint(f);
    return (ushort_t)((x + 0x7fffu + ((x >> 16) & 1u)) >> 16);   // RNE
}

// ---------------------------------------------------------------------------
// bf16 MFMA GEMM (m97 structure): C[M,N] = act(A[M,K] @ BT[N,K]^T + bias)
// A, BT bf16 (K%32==0, lda=ldb=K); C bf16; bias fp32. M%128==0, N%128==0.
// 128x128 tile, BK=32, 256 threads (4 waves, 2x2 of 64x64), global_load_lds.
// ---------------------------------------------------------------------------
#define GBM 128
#define GBN 128
#define GBK 32

__global__ __launch_bounds__(256) void gemm_bf16_kernel(
    const ushort_t* __restrict__ A, const ushort_t* __restrict__ BT,
    const float* __restrict__ bias, ushort_t* __restrict__ C,
    int M, int N, int K, int act)
{
    __shared__ ushort_t Asl[GBM * GBK];
    __shared__ ushort_t Bsl[GBN * GBK];

    const int tid  = threadIdx.x;
    const int wave = tid >> 6;
    const int lane = tid & 63;
    const int wr   = wave >> 1;        // 0..1
    const int wc   = wave & 1;         // 0..1
    const int row0 = blockIdx.y * GBM;
    const int col0 = blockIdx.x * GBN;

    const int srow = lane >> 2;        // 0..15 (row within 16-row staging group)
    const int skel = (lane & 3) * 8;   // bf16 elem offset within row

    f32x4_t acc[4][4] = {};

    for (int k0 = 0; k0 < K; k0 += GBK) {
        __syncthreads();               // protect LDS from previous iteration's reads
        #pragma unroll
        for (int t = 0; t < 2; ++t) {
            const int rg = wave * 32 + t * 16;                   // wave-uniform
            const ushort_t* ga = A + (size_t)(row0 + rg + srow) * K + k0 + skel;
            __builtin_amdgcn_global_load_lds(
                (const __attribute__((address_space(1))) void*)ga,
                (__attribute__((address_space(3))) void*)&Asl[rg * GBK], 16, 0, 0);
            const ushort_t* gb = BT + (size_t)(col0 + rg + srow) * K + k0 + skel;
            __builtin_amdgcn_global_load_lds(
                (const __attribute__((address_space(1))) void*)gb,
                (__attribute__((address_space(3))) void*)&Bsl[rg * GBK], 16, 0, 0);
        }
        __syncthreads();               // drains vmcnt (global_load_lds) + barrier

        const int fr = lane & 15;      // m (A) / n (B) within 16
        const int fq = lane >> 4;      // quad -> k offset fq*8
        bf16x8_t av[4], bv[4];
        #pragma unroll
        for (int i = 0; i < 4; ++i)
            av[i] = *(const bf16x8_t*)&Asl[(wr * 64 + i * 16 + fr) * GBK + fq * 8];
        #pragma unroll
        for (int j = 0; j < 4; ++j)
            bv[j] = *(const bf16x8_t*)&Bsl[(wc * 64 + j * 16 + fr) * GBK + fq * 8];
        #pragma unroll
        for (int i = 0; i < 4; ++i)
            #pragma unroll
            for (int j = 0; j < 4; ++j)
                acc[i][j] = __builtin_amdgcn_mfma_f32_16x16x32_bf16(
                    av[i], bv[j], acc[i][j], 0, 0, 0);
    }

    // epilogue: C/D layout col=lane&15, row=(lane>>4)*4+reg
    const int fr = lane & 15;
    const int fq = lane >> 4;
    #pragma unroll
    for (int i = 0; i < 4; ++i) {
        #pragma unroll
        for (int j = 0; j < 4; ++j) {
            const int gn = col0 + wc * 64 + j * 16 + fr;
            const float bb = bias ? bias[gn] : 0.0f;
            #pragma unroll
            for (int r = 0; r < 4; ++r) {
                const int gm = row0 + wr * 64 + i * 16 + fq * 4 + r;
                float v = acc[i][j][r] + bb;
                if (act == ACT_RELU)     v = fmaxf(v, 0.0f);
                else if (act == ACT_ELU) v = (v > 0.0f) ? v : (expf(v) - 1.0f);
                C[(size_t)gm * N + gn] = f2b(v);
            }
        }
    }
}

// ---------------------------------------------------------------------------
// fp32 [R][Cin] (optional rowscale) -> bf16 [R][Cpad], zero-padded
// ---------------------------------------------------------------------------
__global__ __launch_bounds__(256) void cast_rows_kernel(
    const float* __restrict__ src, const float* __restrict__ rowscale,
    ushort_t* __restrict__ dst, int R, int Cin, int Cpad)
{
    int idx = blockIdx.x * 256 + threadIdx.x;
    if (idx >= R * Cpad) return;
    int r = idx / Cpad, c = idx - r * Cpad;
    float v = 0.0f;
    if (c < Cin) {
        v = src[(size_t)r * Cin + c];
        if (rowscale) v *= rowscale[r];
    }
    dst[idx] = f2b(v);
}

// ---------------------------------------------------------------------------
// fp32 W[K][N] -> bf16 WT[N][Kpad] (transpose + pad), 32x32 LDS tiles
// ---------------------------------------------------------------------------
__global__ __launch_bounds__(256) void castT_kernel(
    const float* __restrict__ W, ushort_t* __restrict__ WT,
    int K, int N, int Kpad)
{
    __shared__ float t[32][33];
    const int nb = blockIdx.x * 32, kb = blockIdx.y * 32;
    const int x = threadIdx.x & 31, y = threadIdx.x >> 5;   // 32 x 8
    #pragma unroll
    for (int yy = 0; yy < 32; yy += 8) {
        int k = kb + y + yy, n = nb + x;
        t[y + yy][x] = (k < K && n < N) ? W[(size_t)k * N + n] : 0.0f;
    }
    __syncthreads();
    #pragma unroll
    for (int yy = 0; yy < 32; yy += 8) {
        int n = nb + y + yy, kk = kb + x;
        if (n < N && kk < Kpad) WT[(size_t)n * Kpad + kk] = f2b(t[x][y + yy]);
    }
}

// ---------------------------------------------------------------------------
// Attention logits: s[n,h] = sum_c h[n,h,c]*a_src[h,c]; one wave per (n,h)
// ---------------------------------------------------------------------------
__global__ __launch_bounds__(256) void attn_dot_kernel(
    const ushort_t* __restrict__ h, const float* __restrict__ a_src,
    const float* __restrict__ a_dst, float* __restrict__ s_out,
    float* __restrict__ d_out, int n_nodes, int H)
{
    const int wave = threadIdx.x >> 6;
    const int lane = threadIdx.x & 63;
    const long pair = (long)blockIdx.x * 4 + wave;
    if (pair >= (long)n_nodes * H) return;
    const int n  = (int)(pair / H);
    const int hd = (int)(pair % H);

    const ushort_t* hp = h + (size_t)n * H * CCH + hd * CCH;
    const float* as = a_src + hd * CCH;
    const float* ad = a_dst + hd * CCH;
    float v0 = b2f(hp[lane]), v1 = b2f(hp[lane + 64]);
    float s = v0 * as[lane] + v1 * as[lane + 64];
    float d = v0 * ad[lane] + v1 * ad[lane + 64];
    #pragma unroll
    for (int o = 32; o > 0; o >>= 1) {
        s += __shfl_xor(s, o, 64);
        d += __shfl_xor(d, o, 64);
    }
    if (lane == 0) { s_out[pair] = s; d_out[pair] = d; }
}

__device__ __forceinline__ unsigned enc_f(float f) {
    unsigned u = __float_as_uint(f);
    return (u >> 31) ? ~u : (u | 0x80000000u);
}
__device__ __forceinline__ float dec_f(unsigned e) {
    return (e >> 31) ? __uint_as_float(e ^ 0x80000000u) : __uint_as_float(~e);
}

// ---------------------------------------------------------------------------
// Fused GAT softmax + aggregation, one block per (graph, head). bf16 in/out.
// ---------------------------------------------------------------------------
__global__ __launch_bounds__(128) void gat_agg_kernel(
    const ushort_t* __restrict__ h, const float* __restrict__ a_s,
    const float* __restrict__ a_d, const int* __restrict__ esrc,
    const int* __restrict__ edst, const float* __restrict__ bias,
    ushort_t* __restrict__ out, int H)
{
    const int g   = blockIdx.x / H;
    const int hd  = blockIdx.x % H;
    const int tid = threadIdx.x;            // 128 threads
    const int base = g * NPG;
    const int HC = H * CCH;

    __shared__ float h_l[NPG][CCH];
    __shared__ float o_l[NPG][CCH];
    __shared__ float as_l[NPG], ad_l[NPG];
    __shared__ unsigned m_l[NPG];
    __shared__ float den_l[NPG];
    __shared__ float sc_l[EPG + NPG];
    __shared__ unsigned char s_l[EPG + NPG], d_l[EPG + NPG];

    for (int r = 0; r < NPG; r++) {
        h_l[r][tid] = b2f(h[(size_t)(base + r) * HC + hd * CCH + tid]);
        o_l[r][tid] = 0.0f;
    }
    if (tid < NPG) {
        as_l[tid]  = a_s[(base + tid) * H + hd];
        ad_l[tid]  = a_d[(base + tid) * H + hd];
        m_l[tid]   = 0u;
        den_l[tid] = 0.0f;
    }
    __syncthreads();

    for (int j = tid; j < EPG + NPG; j += 128) {
        int s, d;
        if (j < EPG) {
            s = esrc[g * EPG + j] - base;
            d = edst[g * EPG + j] - base;
        } else {
            s = d = j - EPG;
        }
        float e = as_l[s] + ad_l[d];
        e = (e >= 0.0f) ? e : 0.2f * e;        // leaky_relu 0.2
        sc_l[j] = e;
        s_l[j] = (unsigned char)s;
        d_l[j] = (unsigned char)d;
        atomicMax(&m_l[d], enc_f(e));
    }
    __syncthreads();

    for (int j = tid; j < EPG + NPG; j += 128) {
        float ex = expf(sc_l[j] - dec_f(m_l[d_l[j]]));
        sc_l[j] = ex;
        atomicAdd(&den_l[d_l[j]], ex);
    }
    __syncthreads();

    for (int j = tid; j < EPG + NPG; j += 128)
        sc_l[j] = sc_l[j] / (den_l[d_l[j]] + 1e-16f);
    __syncthreads();

    for (int j = 0; j < EPG + NPG; j++)
        o_l[d_l[j]][tid] += sc_l[j] * h_l[s_l[j]][tid];

    float b = bias[hd * CCH + tid];
    for (int r = 0; r < NPG; r++) {
        float v = o_l[r][tid] + b;
        v = (v > 0.0f) ? v : (expf(v) - 1.0f);   // elu
        out[(size_t)(base + r) * HC + hd * CCH + tid] = f2b(v);
    }
}

// ---------------------------------------------------------------------------
// Global max pool over 32 nodes per graph (bf16 in/out)
// ---------------------------------------------------------------------------
__global__ __launch_bounds__(128) void maxpool_kernel(
    const ushort_t* __restrict__ x, ushort_t* __restrict__ out)
{
    const int g = blockIdx.x;
    const int c = threadIdx.x;
    float m = -INFINITY;
    for (int r = 0; r < NPG; r++)
        m = fmaxf(m, b2f(x[(size_t)(g * NPG + r) * CCH + c]));
    out[g * CCH + c] = f2b(m);
}

// ---------------------------------------------------------------------------
// Per-row inverse L2 norm (gene branch, fp32 input)
// ---------------------------------------------------------------------------
__global__ __launch_bounds__(256) void rownorm_kernel(
    const float* __restrict__ x, float* __restrict__ inv, int K)
{
    const int row = blockIdx.x;
    const int tid = threadIdx.x;
    const float* xp = x + (size_t)row * K;
    float s = 0.f;
    for (int k = tid; k < K; k += 256) { float v = xp[k]; s += v * v; }
    __shared__ float red[256];
    red[tid] = s;
    __syncthreads();
    for (int o = 128; o > 0; o >>= 1) {
        if (tid < o) red[tid] += red[tid + o];
        __syncthreads();
    }
    if (tid == 0) inv[row] = 1.0f / fmaxf(sqrtf(red[0]), 1e-12f);
}

// ---------------------------------------------------------------------------
// Column-block copy helpers (into concat buffers)
// ---------------------------------------------------------------------------
__global__ __launch_bounds__(256) void copyb_kernel(
    ushort_t* __restrict__ dst, int ld, int off,
    const ushort_t* __restrict__ src, int rows, int cols)
{
    int idx = blockIdx.x * 256 + threadIdx.x;
    if (idx >= rows * cols) return;
    int r = idx / cols, c = idx - r * cols;
    dst[(size_t)r * ld + off + c] = src[idx];
}

__global__ __launch_bounds__(256) void castcols_kernel(
    ushort_t* __restrict__ dst, int ld, int off,
    const float* __restrict__ src, int rows, int cols)
{
    int idx = blockIdx.x * 256 + threadIdx.x;
    if (idx >= rows * cols) return;
    int r = idx / cols, c = idx - r * cols;
    dst[(size_t)r * ld + off + c] = f2b(src[idx]);
}

// ---------------------------------------------------------------------------
// Final N_TASKS=1: out[b] = y[b,:256] . w + bout   (y bf16)
// ---------------------------------------------------------------------------
__global__ __launch_bounds__(256) void final_kernel(
    const ushort_t* __restrict__ y, const float* __restrict__ w,
    const float* __restrict__ b, float* __restrict__ out)
{
    const int row = blockIdx.x;
    const int tid = threadIdx.x;
    float v = b2f(y[(size_t)row * 256 + tid]) * w[tid];
    __shared__ float red[256];
    red[tid] = v;
    __syncthreads();
    for (int o = 128; o > 0; o >>= 1) {
        if (tid < o) red[tid] += red[tid + o];
        __syncthreads();
    }
    if (tid == 0) out[row] = red[0] + b[0];
}

// ---------------------------------------------------------------------------
// Host side
// ---------------------------------------------------------------------------
static inline void launch_gemm(const ushort_t* A, const ushort_t* BT,
                               const float* bias, ushort_t* C,
                               int M, int N, int K, int act, hipStream_t stream)
{
    dim3 grid(N / GBN, M / GBM);
    gemm_bf16_kernel<<<grid, 256, 0, stream>>>(A, BT, bias, C, M, N, K, act);
}

static inline void launch_castT(const float* W, ushort_t* WT, int K, int N,
                                int Kpad, hipStream_t stream)
{
    dim3 grid((N + 31) / 32, (Kpad + 31) / 32);
    castT_kernel<<<grid, 256, 0, stream>>>(W, WT, K, N, Kpad);
}

extern "C" void kernel_launch(void* const* d_in, const int* in_sizes, int n_in,
                              void* d_out, int out_size, void* d_ws, size_t ws_size,
                              hipStream_t stream)
{
    const float* x1      = (const float*)d_in[0];
    const float* x2      = (const float*)d_in[1];
    const float* gene    = (const float*)d_in[2];
    const float* drr     = (const float*)d_in[3];
    const float* drc     = (const float*)d_in[4];
    const float* prot    = (const float*)d_in[5];
    const int*   ei1     = (const int*)d_in[6];
    const int*   ei2     = (const int*)d_in[7];
    const float* W_gat1  = (const float*)d_in[9];
    const float* b_gat1  = (const float*)d_in[10];
    const float* a_src1  = (const float*)d_in[11];
    const float* a_dst1  = (const float*)d_in[12];
    const float* W_gat2  = (const float*)d_in[13];
    const float* b_gat2  = (const float*)d_in[14];
    const float* a_src2  = (const float*)d_in[15];
    const float* a_dst2  = (const float*)d_in[16];
    const float* W_fcg   = (const float*)d_in[17];
    const float* b_fcg   = (const float*)d_in[18];
    const float* Wr1     = (const float*)d_in[19];
    const float* br1     = (const float*)d_in[20];
    const float* Wr2     = (const float*)d_in[21];
    const float* br2     = (const float*)d_in[22];
    const float* Wr3     = (const float*)d_in[23];
    const float* br3     = (const float*)d_in[24];
    const float* Wp1     = (const float*)d_in[25];
    const float* bp1     = (const float*)d_in[26];
    const float* Wp2     = (const float*)d_in[27];
    const float* bp2     = (const float*)d_in[28];
    const float* Wp3     = (const float*)d_in[29];
    const float* bp3     = (const float*)d_in[30];
    const float* Wdrr    = (const float*)d_in[31];
    const float* bdrr    = (const float*)d_in[32];
    const float* Wdrc    = (const float*)d_in[33];
    const float* bdrc    = (const float*)d_in[34];
    const float* Wf1     = (const float*)d_in[35];
    const float* bf1     = (const float*)d_in[36];
    const float* Wf2     = (const float*)d_in[37];
    const float* bf2     = (const float*)d_in[38];
    const float* Wout    = (const float*)d_in[39];
    const float* bout    = (const float*)d_in[40];
    float* outp = (float*)d_out;

    char* ws = (char*)d_ws;
    size_t off = 0;
    auto alloc = [&](size_t bytes) -> char* {
        char* r = ws + off;
        off += (bytes + 255) & ~(size_t)255;
        return r;
    };

    ushort_t* WT_r1  = (ushort_t*)alloc((size_t)2048 * GENEP * 2);
    char*     arenaA = alloc(67108864);   // h1 [32768x1024]; later gene/prot/ybuf
    char*     arenaB = alloc(67108864);   // go1 [32768x1024]; later MLP temporaries
    ushort_t* WT_p1  = (ushort_t*)alloc((size_t)1024 * PROT * 2);
    ushort_t* WT_drr = (ushort_t*)alloc((size_t)2176 * 2176 * 2);
    ushort_t* WT_drc = (ushort_t*)alloc((size_t)2176 * 2176 * 2);
    ushort_t* WT_f1  = (ushort_t*)alloc((size_t)512 * 4864 * 2);
    ushort_t* WT_r2  = (ushort_t*)alloc((size_t)512 * 2048 * 2);
    ushort_t* WT_p2  = (ushort_t*)alloc((size_t)512 * 1024 * 2);
    ushort_t* WT_g1  = (ushort_t*)alloc((size_t)1024 * 96 * 2);
    ushort_t* WT_g2  = (ushort_t*)alloc((size_t)128 * 1024 * 2);
    ushort_t* WT_fcg = (ushort_t*)alloc((size_t)128 * 128 * 2);
    ushort_t* WT_r3  = (ushort_t*)alloc((size_t)256 * 512 * 2);
    ushort_t* WT_p3  = (ushort_t*)alloc((size_t)256 * 512 * 2);
    ushort_t* WT_f2  = (ushort_t*)alloc((size_t)256 * 512 * 2);
    ushort_t* xb     = (ushort_t*)alloc((size_t)NNODES * 96 * 2);
    ushort_t* h2     = (ushort_t*)alloc((size_t)NNODES * 128 * 2);
    ushort_t* go2    = (ushort_t*)alloc((size_t)NNODES * 128 * 2);
    ushort_t* pooled = (ushort_t*)alloc((size_t)BATCH * 128 * 2);
    ushort_t* g1b    = (ushort_t*)alloc((size_t)BATCH * 128 * 2);
    ushort_t* g2b    = (ushort_t*)alloc((size_t)BATCH * 128 * 2);
    float*    asrcb  = (float*)alloc((size_t)NNODES * NHEAD * 4);
    float*    adstb  = (float*)alloc((size_t)NNODES * NHEAD * 4);
    float*    as2b   = (float*)alloc((size_t)NNODES * 4);
    float*    ad2b   = (float*)alloc((size_t)NNODES * 4);
    float*    invn   = (float*)alloc((size_t)BATCH * 4);
    ushort_t* cvec   = (ushort_t*)alloc((size_t)BATCH * 256 * 2);
    ushort_t* pvec   = (ushort_t*)alloc((size_t)BATCH * 256 * 2);
    ushort_t* y1     = (ushort_t*)alloc((size_t)BATCH * 512 * 2);
    ushort_t* y2     = (ushort_t*)alloc((size_t)BATCH * 256 * 2);

    // arena aliases (phase-disjoint lifetimes)
    ushort_t* h1      = (ushort_t*)arenaA;                    // drug phase
    ushort_t* gene_nb = (ushort_t*)arenaA;                    // gene GEMM input
    ushort_t* protb   = (ushort_t*)(arenaA + 37748736);       // prot GEMM input
    ushort_t* ybuf    = (ushort_t*)(arenaA + 52428800);       // predictor concat
    ushort_t* go1     = (ushort_t*)arenaB;                    // drug phase
    ushort_t* cell1   = (ushort_t*)(arenaB + 0);
    ushort_t* cell2   = (ushort_t*)(arenaB + 4194304);
    ushort_t* p1b     = (ushort_t*)(arenaB + 5242880);
    ushort_t* p2b     = (ushort_t*)(arenaB + 7340032);
    ushort_t* cat1    = (ushort_t*)(arenaB + 8388608);
    ushort_t* cat2    = (ushort_t*)(arenaB + 12845056);
    ushort_t* d1      = (ushort_t*)(arenaB + 17301504);
    ushort_t* d2      = (ushort_t*)(arenaB + 21757952);

    const int E = in_sizes[6] / 2;   // 131072

    // ---------------- weight casts (fp32 [K][N] -> bf16 [N][Kpad]) ----------
    launch_castT(W_gat1, WT_g1, INFEAT, 1024, 96, stream);
    launch_castT(W_gat2, WT_g2, 1024, 128, 1024, stream);
    launch_castT(W_fcg,  WT_fcg, 128, 128, 128, stream);
    launch_castT(Wr1, WT_r1, GENE, 2048, GENEP, stream);
    launch_castT(Wr2, WT_r2, 2048, 512, 2048, stream);
    launch_castT(Wr3, WT_r3, 512, 256, 512, stream);
    launch_castT(Wp1, WT_p1, PROT, 1024, PROT, stream);
    launch_castT(Wp2, WT_p2, 1024, 512, 1024, stream);
    launch_castT(Wp3, WT_p3, 512, 256, 512, stream);
    launch_castT(Wdrr, WT_drr, 2176, 2176, 2176, stream);
    launch_castT(Wdrc, WT_drc, 2176, 2176, 2176, stream);
    launch_castT(Wf1, WT_f1, 4864, 512, 4864, stream);
    launch_castT(Wf2, WT_f2, 512, 256, 512, stream);

    // ---------------- drug branches ----------------
    for (int drug = 0; drug < 2; drug++) {
        const float* x  = drug ? x2 : x1;
        const int*   es = (drug ? ei2 : ei1);
        const int*   ed = es + E;
        ushort_t*    gv = drug ? g2b : g1b;

        cast_rows_kernel<<<(NNODES * 96 + 255) / 256, 256, 0, stream>>>(
            x, nullptr, xb, NNODES, INFEAT, 96);
        launch_gemm(xb, WT_g1, nullptr, h1, NNODES, 1024, 96, ACT_NONE, stream);
        attn_dot_kernel<<<NNODES * NHEAD / 4, 256, 0, stream>>>(
            h1, a_src1, a_dst1, asrcb, adstb, NNODES, NHEAD);
        gat_agg_kernel<<<BATCH * NHEAD, 128, 0, stream>>>(
            h1, asrcb, adstb, es, ed, b_gat1, go1, NHEAD);

        launch_gemm(go1, WT_g2, nullptr, h2, NNODES, 128, 1024, ACT_NONE, stream);
        attn_dot_kernel<<<NNODES / 4, 256, 0, stream>>>(
            h2, a_src2, a_dst2, as2b, ad2b, NNODES, 1);
        gat_agg_kernel<<<BATCH, 128, 0, stream>>>(
            h2, as2b, ad2b, es, ed, b_gat2, go2, 1);

        maxpool_kernel<<<BATCH, 128, 0, stream>>>(go2, pooled);
        launch_gemm(pooled, WT_fcg, b_fcg, gv, BATCH, 128, 128, ACT_RELU, stream);
    }

    // ---------------- gene branch ----------------
    rownorm_kernel<<<BATCH, 256, 0, stream>>>(gene, invn, GENE);
    cast_rows_kernel<<<(BATCH * GENEP + 255) / 256, 256, 0, stream>>>(
        gene, invn, gene_nb, BATCH, GENE, GENEP);
    launch_gemm(gene_nb, WT_r1, br1, cell1, BATCH, 2048, GENEP, ACT_RELU, stream);
    launch_gemm(cell1, WT_r2, br2, cell2, BATCH, 512, 2048, ACT_RELU, stream);
    launch_gemm(cell2, WT_r3, br3, cvec, BATCH, 256, 512, ACT_RELU, stream);

    // ---------------- protein branch ----------------
    cast_rows_kernel<<<(BATCH * PROT + 255) / 256, 256, 0, stream>>>(
        prot, nullptr, protb, BATCH, PROT, PROT);
    launch_gemm(protb, WT_p1, bp1, p1b, BATCH, 1024, PROT, ACT_ELU, stream);
    launch_gemm(p1b, WT_p2, bp2, p2b, BATCH, 512, 1024, ACT_ELU, stream);
    launch_gemm(p2b, WT_p3, bp3, pvec, BATCH, 256, 512, ACT_RELU, stream);

    // ---------------- fingerprint fusion ----------------
    {
        int n = BATCH * CCH;
        copyb_kernel<<<(n + 255) / 256, 256, 0, stream>>>(cat1, 2176, 0, g1b, BATCH, CCH);
        copyb_kernel<<<(n + 255) / 256, 256, 0, stream>>>(cat2, 2176, 0, g2b, BATCH, CCH);
        n = BATCH * FPD;
        castcols_kernel<<<(n + 255) / 256, 256, 0, stream>>>(cat1, 2176, CCH, drr, BATCH, FPD);
        castcols_kernel<<<(n + 255) / 256, 256, 0, stream>>>(cat2, 2176, CCH, drc, BATCH, FPD);
    }
    launch_gemm(cat1, WT_drr, bdrr, d1, BATCH, 2176, 2176, ACT_RELU, stream);
    launch_gemm(cat2, WT_drc, bdrc, d2, BATCH, 2176, 2176, ACT_RELU, stream);

    // ---------------- concat + predictor ----------------
    {
        int n = BATCH * 2176;
        copyb_kernel<<<(n + 255) / 256, 256, 0, stream>>>(ybuf, 4864, 0,    d1, BATCH, 2176);
        copyb_kernel<<<(n + 255) / 256, 256, 0, stream>>>(ybuf, 4864, 2176, d2, BATCH, 2176);
        n = BATCH * 256;
        copyb_kernel<<<(n + 255) / 256, 256, 0, stream>>>(ybuf, 4864, 4352, cvec, BATCH, 256);
        copyb_kernel<<<(n + 255) / 256, 256, 0, stream>>>(ybuf, 4864, 4608, pvec, BATCH, 256);
    }
    launch_gemm(ybuf, WT_f1, bf1, y1, BATCH, 512, 4864, ACT_RELU, stream);
    launch_gemm(y1, WT_f2, bf2, y2, BATCH, 256, 512, ACT_RELU, stream);
    final_kernel<<<BATCH, 256, 0, stream>>>(y2, Wout, bout, outp);
}

// Round 3
// 1473.804 us; speedup vs baseline: 3.2572x; 1.5916x over previous
//
#include <hip/hip_runtime.h>
#include <math.h>

// ---------------------------------------------------------------------------
// Model dims (fixed by the reference)
// ---------------------------------------------------------------------------
#define BATCH   1024
#define NPG     32
#define NNODES  (BATCH * NPG)      // 32768 per drug
#define EPG     128
#define INFEAT  78
#define CCH     128
#define NHEAD   8
#define GENE    18000
#define GENEP   18016              // padded to %32
#define PROT    6688
#define FPD     2048

#define ACT_NONE 0
#define ACT_RELU 1
#define ACT_ELU  2

typedef unsigned short ushort_t;
typedef __bf16 bf16x8_t __attribute__((ext_vector_type(8)));
typedef float  f32x4_t  __attribute__((ext_vector_type(4)));

__device__ __forceinline__ float b2f(ushort_t u) {
    return __uint_as_float(((unsigned)u) << 16);
}
__device__ __forceinline__ ushort_t f2b(float f) {
    unsigned x = __float_as_uint(f);
    return (ushort_t)((x + 0x7fffu + ((x >> 16) & 1u)) >> 16);   // RNE
}

// ---------------------------------------------------------------------------
// bf16 MFMA GEMM (m97 structure): C[M,N] = act(A[M,K] @ BT[N,K]^T + bias)
// A, BT bf16 (K%32==0); C bf16; bias fp32. M%128==0, N%128==0.
// 128x128 tile, BK=32, 256 threads (2x2 waves of 64x64), global_load_lds.
// ---------------------------------------------------------------------------
#define GBM 128
#define GBN 128
#define GBK 32

__device__ __forceinline__ void gemm_core(
    const ushort_t* __restrict__ A, const ushort_t* __restrict__ BT,
    int K, int kb, int ke, int row0, int col0,
    ushort_t* Asl, ushort_t* Bsl, f32x4_t acc[4][4])
{
    const int tid  = threadIdx.x;
    const int wave = tid >> 6;
    const int lane = tid & 63;
    const int wr   = wave >> 1;
    const int wc   = wave & 1;
    const int srow = lane >> 2;        // 0..15
    const int skel = (lane & 3) * 8;   // bf16 elem offset

    for (int k0 = kb; k0 < ke; k0 += GBK) {
        __syncthreads();               // protect LDS from previous iteration
        #pragma unroll
        for (int t = 0; t < 2; ++t) {
            const int rg = wave * 32 + t * 16;                   // wave-uniform
            const ushort_t* ga = A + (size_t)(row0 + rg + srow) * K + k0 + skel;
            __builtin_amdgcn_global_load_lds(
                (const __attribute__((address_space(1))) void*)ga,
                (__attribute__((address_space(3))) void*)&Asl[rg * GBK], 16, 0, 0);
            const ushort_t* gb = BT + (size_t)(col0 + rg + srow) * K + k0 + skel;
            __builtin_amdgcn_global_load_lds(
                (const __attribute__((address_space(1))) void*)gb,
                (__attribute__((address_space(3))) void*)&Bsl[rg * GBK], 16, 0, 0);
        }
        __syncthreads();

        const int fr = lane & 15;
        const int fq = lane >> 4;
        bf16x8_t av[4], bv[4];
        #pragma unroll
        for (int i = 0; i < 4; ++i)
            av[i] = *(const bf16x8_t*)&Asl[(wr * 64 + i * 16 + fr) * GBK + fq * 8];
        #pragma unroll
        for (int j = 0; j < 4; ++j)
            bv[j] = *(const bf16x8_t*)&Bsl[(wc * 64 + j * 16 + fr) * GBK + fq * 8];
        #pragma unroll
        for (int i = 0; i < 4; ++i)
            #pragma unroll
            for (int j = 0; j < 4; ++j)
                acc[i][j] = __builtin_amdgcn_mfma_f32_16x16x32_bf16(
                    av[i], bv[j], acc[i][j], 0, 0, 0);
    }
}

__global__ __launch_bounds__(256) void gemm_bf16_kernel(
    const ushort_t* __restrict__ A, const ushort_t* __restrict__ BT,
    const float* __restrict__ bias, ushort_t* __restrict__ C,
    int M, int N, int K, int act)
{
    __shared__ ushort_t Asl[GBM * GBK];
    __shared__ ushort_t Bsl[GBN * GBK];
    const int lane = threadIdx.x & 63;
    const int wave = threadIdx.x >> 6;
    const int wr = wave >> 1, wc = wave & 1;
    const int row0 = blockIdx.y * GBM;
    const int col0 = blockIdx.x * GBN;

    f32x4_t acc[4][4] = {};
    gemm_core(A, BT, K, 0, K, row0, col0, Asl, Bsl, acc);

    const int fr = lane & 15;
    const int fq = lane >> 4;
    #pragma unroll
    for (int i = 0; i < 4; ++i) {
        #pragma unroll
        for (int j = 0; j < 4; ++j) {
            const int gn = col0 + wc * 64 + j * 16 + fr;
            const float bb = bias ? bias[gn] : 0.0f;
            #pragma unroll
            for (int r = 0; r < 4; ++r) {
                const int gm = row0 + wr * 64 + i * 16 + fq * 4 + r;
                float v = acc[i][j][r] + bb;
                if (act == ACT_RELU)     v = fmaxf(v, 0.0f);
                else if (act == ACT_ELU) v = (v > 0.0f) ? v : (expf(v) - 1.0f);
                C[(size_t)gm * N + gn] = f2b(v);
            }
        }
    }
}

// split-K variant: grid.z = chunk index, fp32 partials out (no bias/act)
__global__ __launch_bounds__(256) void gemm_bf16_part_kernel(
    const ushort_t* __restrict__ A, const ushort_t* __restrict__ BT,
    float* __restrict__ part, int M, int N, int K, int KC)
{
    __shared__ ushort_t Asl[GBM * GBK];
    __shared__ ushort_t Bsl[GBN * GBK];
    const int lane = threadIdx.x & 63;
    const int wave = threadIdx.x >> 6;
    const int wr = wave >> 1, wc = wave & 1;
    const int row0 = blockIdx.y * GBM;
    const int col0 = blockIdx.x * GBN;
    const int z    = blockIdx.z;
    const int kb   = z * KC;
    const int ke   = min(K, kb + KC);

    f32x4_t acc[4][4] = {};
    gemm_core(A, BT, K, kb, ke, row0, col0, Asl, Bsl, acc);

    const int fr = lane & 15;
    const int fq = lane >> 4;
    float* po = part + (size_t)z * M * N;
    #pragma unroll
    for (int i = 0; i < 4; ++i)
        #pragma unroll
        for (int j = 0; j < 4; ++j) {
            const int gn = col0 + wc * 64 + j * 16 + fr;
            #pragma unroll
            for (int r = 0; r < 4; ++r) {
                const int gm = row0 + wr * 64 + i * 16 + fq * 4 + r;
                po[(size_t)gm * N + gn] = acc[i][j][r];
            }
        }
}

// sum S partials + bias + act -> bf16
__global__ __launch_bounds__(256) void reduce_kernel(
    const float* __restrict__ part, const float* __restrict__ bias,
    ushort_t* __restrict__ C, int MN, int N, int S, int act)
{
    int i4 = (blockIdx.x * 256 + threadIdx.x) * 4;
    if (i4 >= MN) return;
    float4 s = *(const float4*)&part[i4];
    for (int z = 1; z < S; ++z) {
        float4 v = *(const float4*)&part[(size_t)z * MN + i4];
        s.x += v.x; s.y += v.y; s.z += v.z; s.w += v.w;
    }
    const int n = i4 % N;
    float o[4] = { s.x, s.y, s.z, s.w };
    if (bias) { o[0] += bias[n]; o[1] += bias[n+1]; o[2] += bias[n+2]; o[3] += bias[n+3]; }
    unsigned pk[2];
    ushort_t r[4];
    #pragma unroll
    for (int k = 0; k < 4; ++k) {
        float v = o[k];
        if (act == ACT_RELU)     v = fmaxf(v, 0.0f);
        else if (act == ACT_ELU) v = (v > 0.0f) ? v : (expf(v) - 1.0f);
        r[k] = f2b(v);
    }
    pk[0] = (unsigned)r[0] | ((unsigned)r[1] << 16);
    pk[1] = (unsigned)r[2] | ((unsigned)r[3] << 16);
    *(uint2*)&C[i4] = make_uint2(pk[0], pk[1]);
}

// ---------------------------------------------------------------------------
// fp32 [R][Cin] (optional rowscale) -> bf16 [R][Cpad], zero-padded
// ---------------------------------------------------------------------------
__global__ __launch_bounds__(256) void cast_rows_kernel(
    const float* __restrict__ src, const float* __restrict__ rowscale,
    ushort_t* __restrict__ dst, int R, int Cin, int Cpad)
{
    int idx = blockIdx.x * 256 + threadIdx.x;
    if (idx >= R * Cpad) return;
    int r = idx / Cpad, c = idx - r * Cpad;
    float v = 0.0f;
    if (c < Cin) {
        v = src[(size_t)r * Cin + c];
        if (rowscale) v *= rowscale[r];
    }
    dst[idx] = f2b(v);
}

// ---------------------------------------------------------------------------
// fp32 W[K][N] -> bf16 WT[N][Kpad] (transpose + pad), 32x32 LDS tiles
// ---------------------------------------------------------------------------
__global__ __launch_bounds__(256) void castT_kernel(
    const float* __restrict__ W, ushort_t* __restrict__ WT,
    int K, int N, int Kpad)
{
    __shared__ float t[32][33];
    const int nb = blockIdx.x * 32, kb = blockIdx.y * 32;
    const int x = threadIdx.x & 31, y = threadIdx.x >> 5;   // 32 x 8
    #pragma unroll
    for (int yy = 0; yy < 32; yy += 8) {
        int k = kb + y + yy, n = nb + x;
        t[y + yy][x] = (k < K && n < N) ? W[(size_t)k * N + n] : 0.0f;
    }
    __syncthreads();
    #pragma unroll
    for (int yy = 0; yy < 32; yy += 8) {
        int n = nb + y + yy, kk = kb + x;
        if (n < N && kk < Kpad) WT[(size_t)n * Kpad + kk] = f2b(t[x][y + yy]);
    }
}

// ---------------------------------------------------------------------------
// Attention logits: s[n,h] = sum_c h[n,h,c]*a_src[h,c]; one wave per (n,h)
// ---------------------------------------------------------------------------
__global__ __launch_bounds__(256) void attn_dot_kernel(
    const ushort_t* __restrict__ h, const float* __restrict__ a_src,
    const float* __restrict__ a_dst, float* __restrict__ s_out,
    float* __restrict__ d_out, int n_nodes, int H)
{
    const int wave = threadIdx.x >> 6;
    const int lane = threadIdx.x & 63;
    const long pair = (long)blockIdx.x * 4 + wave;
    if (pair >= (long)n_nodes * H) return;
    const int n  = (int)(pair / H);
    const int hd = (int)(pair % H);

    const ushort_t* hp = h + (size_t)n * H * CCH + hd * CCH;
    const float* as = a_src + hd * CCH;
    const float* ad = a_dst + hd * CCH;
    float v0 = b2f(hp[lane]), v1 = b2f(hp[lane + 64]);
    float s = v0 * as[lane] + v1 * as[lane + 64];
    float d = v0 * ad[lane] + v1 * ad[lane + 64];
    #pragma unroll
    for (int o = 32; o > 0; o >>= 1) {
        s += __shfl_xor(s, o, 64);
        d += __shfl_xor(d, o, 64);
    }
    if (lane == 0) { s_out[pair] = s; d_out[pair] = d; }
}

__device__ __forceinline__ unsigned enc_f(float f) {
    unsigned u = __float_as_uint(f);
    return (u >> 31) ? ~u : (u | 0x80000000u);
}
__device__ __forceinline__ float dec_f(unsigned e) {
    return (e >> 31) ? __uint_as_float(e ^ 0x80000000u) : __uint_as_float(~e);
}

// ---------------------------------------------------------------------------
// Fused GAT softmax + aggregation, one block per (graph, head). bf16 in/out.
// ---------------------------------------------------------------------------
__global__ __launch_bounds__(128) void gat_agg_kernel(
    const ushort_t* __restrict__ h, const float* __restrict__ a_s,
    const float* __restrict__ a_d, const int* __restrict__ esrc,
    const int* __restrict__ edst, const float* __restrict__ bias,
    ushort_t* __restrict__ out, int H)
{
    const int g   = blockIdx.x / H;
    const int hd  = blockIdx.x % H;
    const int tid = threadIdx.x;            // 128 threads
    const int base = g * NPG;
    const int HC = H * CCH;

    __shared__ float h_l[NPG][CCH];
    __shared__ float o_l[NPG][CCH];
    __shared__ float as_l[NPG], ad_l[NPG];
    __shared__ unsigned m_l[NPG];
    __shared__ float den_l[NPG];
    __shared__ float sc_l[EPG + NPG];
    __shared__ unsigned char s_l[EPG + NPG], d_l[EPG + NPG];

    for (int r = 0; r < NPG; r++) {
        h_l[r][tid] = b2f(h[(size_t)(base + r) * HC + hd * CCH + tid]);
        o_l[r][tid] = 0.0f;
    }
    if (tid < NPG) {
        as_l[tid]  = a_s[(base + tid) * H + hd];
        ad_l[tid]  = a_d[(base + tid) * H + hd];
        m_l[tid]   = 0u;
        den_l[tid] = 0.0f;
    }
    __syncthreads();

    for (int j = tid; j < EPG + NPG; j += 128) {
        int s, d;
        if (j < EPG) {
            s = esrc[g * EPG + j] - base;
            d = edst[g * EPG + j] - base;
        } else {
            s = d = j - EPG;
        }
        float e = as_l[s] + ad_l[d];
        e = (e >= 0.0f) ? e : 0.2f * e;        // leaky_relu 0.2
        sc_l[j] = e;
        s_l[j] = (unsigned char)s;
        d_l[j] = (unsigned char)d;
        atomicMax(&m_l[d], enc_f(e));
    }
    __syncthreads();

    for (int j = tid; j < EPG + NPG; j += 128) {
        float ex = expf(sc_l[j] - dec_f(m_l[d_l[j]]));
        sc_l[j] = ex;
        atomicAdd(&den_l[d_l[j]], ex);
    }
    __syncthreads();

    for (int j = tid; j < EPG + NPG; j += 128)
        sc_l[j] = sc_l[j] / (den_l[d_l[j]] + 1e-16f);
    __syncthreads();

    for (int j = 0; j < EPG + NPG; j++)
        o_l[d_l[j]][tid] += sc_l[j] * h_l[s_l[j]][tid];

    float b = bias[hd * CCH + tid];
    for (int r = 0; r < NPG; r++) {
        float v = o_l[r][tid] + b;
        v = (v > 0.0f) ? v : (expf(v) - 1.0f);   // elu
        out[(size_t)(base + r) * HC + hd * CCH + tid] = f2b(v);
    }
}

// ---------------------------------------------------------------------------
// Global max pool over 32 nodes per graph (bf16 in/out)
// ---------------------------------------------------------------------------
__global__ __launch_bounds__(128) void maxpool_kernel(
    const ushort_t* __restrict__ x, ushort_t* __restrict__ out)
{
    const int g = blockIdx.x;
    const int c = threadIdx.x;
    float m = -INFINITY;
    for (int r = 0; r < NPG; r++)
        m = fmaxf(m, b2f(x[(size_t)(g * NPG + r) * CCH + c]));
    out[g * CCH + c] = f2b(m);
}

// ---------------------------------------------------------------------------
// Per-row inverse L2 norm (gene branch, fp32 input)
// ---------------------------------------------------------------------------
__global__ __launch_bounds__(256) void rownorm_kernel(
    const float* __restrict__ x, float* __restrict__ inv, int K)
{
    const int row = blockIdx.x;
    const int tid = threadIdx.x;
    const float* xp = x + (size_t)row * K;
    float s = 0.f;
    for (int k = tid; k < K; k += 256) { float v = xp[k]; s += v * v; }
    __shared__ float red[256];
    red[tid] = s;
    __syncthreads();
    for (int o = 128; o > 0; o >>= 1) {
        if (tid < o) red[tid] += red[tid + o];
        __syncthreads();
    }
    if (tid == 0) inv[row] = 1.0f / fmaxf(sqrtf(red[0]), 1e-12f);
}

// ---------------------------------------------------------------------------
// Column-block copy helpers (into concat buffers)
// ---------------------------------------------------------------------------
__global__ __launch_bounds__(256) void copyb_kernel(
    ushort_t* __restrict__ dst, int ld, int off,
    const ushort_t* __restrict__ src, int rows, int cols)
{
    int idx = blockIdx.x * 256 + threadIdx.x;
    if (idx >= rows * cols) return;
    int r = idx / cols, c = idx - r * cols;
    dst[(size_t)r * ld + off + c] = src[idx];
}

__global__ __launch_bounds__(256) void castcols_kernel(
    ushort_t* __restrict__ dst, int ld, int off,
    const float* __restrict__ src, int rows, int cols)
{
    int idx = blockIdx.x * 256 + threadIdx.x;
    if (idx >= rows * cols) return;
    int r = idx / cols, c = idx - r * cols;
    dst[(size_t)r * ld + off + c] = f2b(src[idx]);
}

// ---------------------------------------------------------------------------
// Final N_TASKS=1: out[b] = y[b,:256] . w + bout   (y bf16)
// ---------------------------------------------------------------------------
__global__ __launch_bounds__(256) void final_kernel(
    const ushort_t* __restrict__ y, const float* __restrict__ w,
    const float* __restrict__ b, float* __restrict__ out)
{
    const int row = blockIdx.x;
    const int tid = threadIdx.x;
    float v = b2f(y[(size_t)row * 256 + tid]) * w[tid];
    __shared__ float red[256];
    red[tid] = v;
    __syncthreads();
    for (int o = 128; o > 0; o >>= 1) {
        if (tid < o) red[tid] += red[tid + o];
        __syncthreads();
    }
    if (tid == 0) out[row] = red[0] + b[0];
}

// ---------------------------------------------------------------------------
// Host side
// ---------------------------------------------------------------------------
static inline void launch_gemm(const ushort_t* A, const ushort_t* BT,
                               const float* bias, ushort_t* C,
                               int M, int N, int K, int act, hipStream_t stream)
{
    dim3 grid(N / GBN, M / GBM);
    gemm_bf16_kernel<<<grid, 256, 0, stream>>>(A, BT, bias, C, M, N, K, act);
}

// split-K GEMM: partials into `part` (fp32), then reduce with bias+act
static inline void launch_gemm_sk(const ushort_t* A, const ushort_t* BT,
                                  const float* bias, ushort_t* C, float* part,
                                  int M, int N, int K, int S, int act,
                                  hipStream_t stream)
{
    if (S <= 1) { launch_gemm(A, BT, bias, C, M, N, K, act, stream); return; }
    const int iters = K / GBK;
    const int ipc   = (iters + S - 1) / S;         // iters per chunk
    const int S_eff = (iters + ipc - 1) / ipc;     // no empty chunks
    const int KC    = ipc * GBK;
    dim3 grid(N / GBN, M / GBM, S_eff);
    gemm_bf16_part_kernel<<<grid, 256, 0, stream>>>(A, BT, part, M, N, K, KC);
    const int MN = M * N;
    reduce_kernel<<<(MN / 4 + 255) / 256, 256, 0, stream>>>(
        part, bias, C, MN, N, S_eff, act);
}

static inline void launch_castT(const float* W, ushort_t* WT, int K, int N,
                                int Kpad, hipStream_t stream)
{
    dim3 grid((N + 31) / 32, (Kpad + 31) / 32);
    castT_kernel<<<grid, 256, 0, stream>>>(W, WT, K, N, Kpad);
}

extern "C" void kernel_launch(void* const* d_in, const int* in_sizes, int n_in,
                              void* d_out, int out_size, void* d_ws, size_t ws_size,
                              hipStream_t stream)
{
    const float* x1      = (const float*)d_in[0];
    const float* x2      = (const float*)d_in[1];
    const float* gene    = (const float*)d_in[2];
    const float* drr     = (const float*)d_in[3];
    const float* drc     = (const float*)d_in[4];
    const float* prot    = (const float*)d_in[5];
    const int*   ei1     = (const int*)d_in[6];
    const int*   ei2     = (const int*)d_in[7];
    const float* W_gat1  = (const float*)d_in[9];
    const float* b_gat1  = (const float*)d_in[10];
    const float* a_src1  = (const float*)d_in[11];
    const float* a_dst1  = (const float*)d_in[12];
    const float* W_gat2  = (const float*)d_in[13];
    const float* b_gat2  = (const float*)d_in[14];
    const float* a_src2  = (const float*)d_in[15];
    const float* a_dst2  = (const float*)d_in[16];
    const float* W_fcg   = (const float*)d_in[17];
    const float* b_fcg   = (const float*)d_in[18];
    const float* Wr1     = (const float*)d_in[19];
    const float* br1     = (const float*)d_in[20];
    const float* Wr2     = (const float*)d_in[21];
    const float* br2     = (const float*)d_in[22];
    const float* Wr3     = (const float*)d_in[23];
    const float* br3     = (const float*)d_in[24];
    const float* Wp1     = (const float*)d_in[25];
    const float* bp1     = (const float*)d_in[26];
    const float* Wp2     = (const float*)d_in[27];
    const float* bp2     = (const float*)d_in[28];
    const float* Wp3     = (const float*)d_in[29];
    const float* bp3     = (const float*)d_in[30];
    const float* Wdrr    = (const float*)d_in[31];
    const float* bdrr    = (const float*)d_in[32];
    const float* Wdrc    = (const float*)d_in[33];
    const float* bdrc    = (const float*)d_in[34];
    const float* Wf1     = (const float*)d_in[35];
    const float* bf1     = (const float*)d_in[36];
    const float* Wf2     = (const float*)d_in[37];
    const float* bf2     = (const float*)d_in[38];
    const float* Wout    = (const float*)d_in[39];
    const float* bout    = (const float*)d_in[40];
    float* outp = (float*)d_out;

    char* ws = (char*)d_ws;
    size_t off = 0;
    auto alloc = [&](size_t bytes) -> char* {
        char* r = ws + off;
        off += (bytes + 255) & ~(size_t)255;
        return r;
    };

    // Phase-overlaid big regions:
    // BIG0 (134 MB): drug phase = go1_full [65536x1024 bf16]
    //                MLP phase  = WT_r1 + gene_nb + cell1 + WT_r2 + WT_p2 + WT_p1
    // BIG1 (67 MB):  drug phase = h1 [32768x1024 bf16] (per-drug, reused)
    //                MLP phase  = split-K fp32 partial buffer (max 67 MB, gene S=8)
    char* BIG0 = alloc(134217728);
    char* BIG1 = alloc(67108864);

    ushort_t* go1f   = (ushort_t*)BIG0;
    ushort_t* h1     = (ushort_t*)BIG1;
    float*    part   = (float*)BIG1;
    ushort_t* WT_r1  = (ushort_t*)(BIG0 + 0);           // 2048x18016 = 73,793,536
    ushort_t* gene_nb= (ushort_t*)(BIG0 + 73793536);    // 1024x18016 = 36,896,768
    ushort_t* cell1  = (ushort_t*)(BIG0 + 110690304);   // 1024x2048  =  4,194,304
    ushort_t* WT_r2  = (ushort_t*)(BIG0 + 114884608);   // 512x2048   =  2,097,152
    ushort_t* WT_p2  = (ushort_t*)(BIG0 + 116981760);   // 512x1024   =  1,048,576
    ushort_t* WT_p1  = (ushort_t*)(BIG0 + 118030336);   // 1024x6688  = 13,697,024 -> 131,727,360

    ushort_t* xb     = (ushort_t*)alloc((size_t)NNODES * 96 * 2);        // per-drug
    char*     h2reg  = alloc((size_t)2 * NNODES * 128 * 2);              // 16.8 MB
    char*     go2reg = alloc((size_t)2 * NNODES * 128 * 2);              // 16.8 MB
    ushort_t* h2f    = (ushort_t*)h2reg;     // drug phase
    ushort_t* protb  = (ushort_t*)h2reg;     // MLP phase alias (13.7 MB <= 16.8)
    ushort_t* go2f   = (ushort_t*)go2reg;    // drug phase
    ushort_t* cat1   = (ushort_t*)go2reg;                                // 4.46 MB
    ushort_t* cat2   = (ushort_t*)(go2reg + 4456448);                    // 4.46 MB
    float*    asrcb  = (float*)alloc((size_t)NNODES * NHEAD * 4);
    float*    adstb  = (float*)alloc((size_t)NNODES * NHEAD * 4);
    float*    as2b   = (float*)alloc((size_t)2 * NNODES * 4);
    float*    ad2b   = (float*)alloc((size_t)2 * NNODES * 4);
    ushort_t* pooled = (ushort_t*)alloc((size_t)2 * BATCH * 128 * 2);
    ushort_t* gpair  = (ushort_t*)alloc((size_t)2 * BATCH * 128 * 2);
    float*    invn   = (float*)alloc((size_t)BATCH * 4);
    ushort_t* cvec   = (ushort_t*)alloc((size_t)BATCH * 256 * 2);
    ushort_t* pvec   = (ushort_t*)alloc((size_t)BATCH * 256 * 2);
    ushort_t* y1     = (ushort_t*)alloc((size_t)BATCH * 512 * 2);
    ushort_t* y2     = (ushort_t*)alloc((size_t)BATCH * 256 * 2);
    ushort_t* WT_g1  = (ushort_t*)alloc((size_t)1024 * 96 * 2);
    ushort_t* WT_g2  = (ushort_t*)alloc((size_t)128 * 1024 * 2);
    ushort_t* WT_fcg = (ushort_t*)alloc((size_t)128 * 128 * 2);
    ushort_t* WT_r3  = (ushort_t*)alloc((size_t)256 * 512 * 2);
    ushort_t* WT_p3  = (ushort_t*)alloc((size_t)256 * 512 * 2);
    ushort_t* WT_f2  = (ushort_t*)alloc((size_t)256 * 512 * 2);
    ushort_t* WT_drr = (ushort_t*)alloc((size_t)2176 * 2176 * 2);
    ushort_t* WT_drc = (ushort_t*)alloc((size_t)2176 * 2176 * 2);
    ushort_t* WT_f1  = (ushort_t*)alloc((size_t)512 * 4864 * 2);
    ushort_t* p1b    = (ushort_t*)alloc((size_t)1024 * 1024 * 2);
    ushort_t* p2b    = (ushort_t*)alloc((size_t)1024 * 512 * 2);
    ushort_t* cell2  = (ushort_t*)alloc((size_t)1024 * 512 * 2);
    ushort_t* d1     = (ushort_t*)alloc((size_t)1024 * 2176 * 2);
    ushort_t* d2     = (ushort_t*)alloc((size_t)1024 * 2176 * 2);
    ushort_t* ybuf   = (ushort_t*)alloc((size_t)1024 * 4864 * 2);
    // total ~296 MB

    const int E = in_sizes[6] / 2;   // 131072

    // ---------------- drug-phase weight casts ----------------
    launch_castT(W_gat1, WT_g1, INFEAT, 1024, 96, stream);
    launch_castT(W_gat2, WT_g2, 1024, 128, 1024, stream);
    launch_castT(W_fcg,  WT_fcg, 128, 128, 128, stream);

    // ---------------- drug branch: GAT1 per drug, write into shared go1f ---
    for (int drug = 0; drug < 2; drug++) {
        const float* x  = drug ? x2 : x1;
        const int*   es = (drug ? ei2 : ei1);
        const int*   ed = es + E;
        ushort_t* go1d = go1f + (size_t)drug * NNODES * 1024;

        cast_rows_kernel<<<(NNODES * 96 + 255) / 256, 256, 0, stream>>>(
            x, nullptr, xb, NNODES, INFEAT, 96);
        launch_gemm(xb, WT_g1, nullptr, h1, NNODES, 1024, 96, ACT_NONE, stream);
        attn_dot_kernel<<<NNODES * NHEAD / 4, 256, 0, stream>>>(
            h1, a_src1, a_dst1, asrcb, adstb, NNODES, NHEAD);
        gat_agg_kernel<<<BATCH * NHEAD, 128, 0, stream>>>(
            h1, asrcb, adstb, es, ed, b_gat1, go1d, NHEAD);
    }

    // ---------------- batched GAT2 GEMM (M=65536 -> 512 blocks) ------------
    launch_gemm(go1f, WT_g2, nullptr, h2f, 2 * NNODES, 128, 1024, ACT_NONE, stream);

    // BIG0 (go1f) now dead -> cast MLP-phase weights into it
    launch_castT(Wr1, WT_r1, GENE, 2048, GENEP, stream);
    launch_castT(Wr2, WT_r2, 2048, 512, 2048, stream);
    launch_castT(Wp1, WT_p1, PROT, 1024, PROT, stream);
    launch_castT(Wp2, WT_p2, 1024, 512, 1024, stream);
    launch_castT(Wr3, WT_r3, 512, 256, 512, stream);
    launch_castT(Wp3, WT_p3, 512, 256, 512, stream);
    launch_castT(Wf2, WT_f2, 512, 256, 512, stream);
    launch_castT(Wdrr, WT_drr, 2176, 2176, 2176, stream);
    launch_castT(Wdrc, WT_drc, 2176, 2176, 2176, stream);
    launch_castT(Wf1, WT_f1, 4864, 512, 4864, stream);

    // ---------------- GAT2 attention + agg + pool + fcg (batched) ----------
    attn_dot_kernel<<<2 * NNODES / 4, 256, 0, stream>>>(
        h2f, a_src2, a_dst2, as2b, ad2b, 2 * NNODES, 1);
    for (int drug = 0; drug < 2; drug++) {
        const int* es = (drug ? ei2 : ei1);
        const int* ed = es + E;
        gat_agg_kernel<<<BATCH, 128, 0, stream>>>(
            h2f + (size_t)drug * NNODES * 128,
            as2b + (size_t)drug * NNODES, ad2b + (size_t)drug * NNODES,
            es, ed, b_gat2, go2f + (size_t)drug * NNODES * 128, 1);
    }
    maxpool_kernel<<<2 * BATCH, 128, 0, stream>>>(go2f, pooled);
    launch_gemm(pooled, WT_fcg, b_fcg, gpair, 2 * BATCH, 128, 128, ACT_RELU, stream);
    // gpair rows [0,1024) = g1, [1024,2048) = g2

    // ---------------- gene branch (split-K) ----------------
    rownorm_kernel<<<BATCH, 256, 0, stream>>>(gene, invn, GENE);
    cast_rows_kernel<<<(BATCH * GENEP + 255) / 256, 256, 0, stream>>>(
        gene, invn, gene_nb, BATCH, GENE, GENEP);
    launch_gemm_sk(gene_nb, WT_r1, br1, cell1, part, BATCH, 2048, GENEP, 8, ACT_RELU, stream);
    launch_gemm_sk(cell1, WT_r2, br2, cell2, part, BATCH, 512, 2048, 8, ACT_RELU, stream);
    launch_gemm_sk(cell2, WT_r3, br3, cvec, part, BATCH, 256, 512, 4, ACT_RELU, stream);

    // ---------------- protein branch (split-K; protb aliases dead h2f) -----
    cast_rows_kernel<<<(BATCH * PROT + 255) / 256, 256, 0, stream>>>(
        prot, nullptr, protb, BATCH, PROT, PROT);
    launch_gemm_sk(protb, WT_p1, bp1, p1b, part, BATCH, 1024, PROT, 8, ACT_ELU, stream);
    launch_gemm_sk(p1b, WT_p2, bp2, p2b, part, BATCH, 512, 1024, 4, ACT_ELU, stream);
    launch_gemm_sk(p2b, WT_p3, bp3, pvec, part, BATCH, 256, 512, 4, ACT_RELU, stream);

    // ---------------- fingerprint fusion (cat aliases dead go2f) -----------
    {
        int n = BATCH * CCH;
        copyb_kernel<<<(n + 255) / 256, 256, 0, stream>>>(cat1, 2176, 0, gpair, BATCH, CCH);
        copyb_kernel<<<(n + 255) / 256, 256, 0, stream>>>(cat2, 2176, 0, gpair + BATCH * CCH, BATCH, CCH);
        n = BATCH * FPD;
        castcols_kernel<<<(n + 255) / 256, 256, 0, stream>>>(cat1, 2176, CCH, drr, BATCH, FPD);
        castcols_kernel<<<(n + 255) / 256, 256, 0, stream>>>(cat2, 2176, CCH, drc, BATCH, FPD);
    }
    launch_gemm_sk(cat1, WT_drr, bdrr, d1, part, BATCH, 2176, 2176, 4, ACT_RELU, stream);
    launch_gemm_sk(cat2, WT_drc, bdrc, d2, part, BATCH, 2176, 2176, 4, ACT_RELU, stream);

    // ---------------- concat + predictor ----------------
    {
        int n = BATCH * 2176;
        copyb_kernel<<<(n + 255) / 256, 256, 0, stream>>>(ybuf, 4864, 0,    d1, BATCH, 2176);
        copyb_kernel<<<(n + 255) / 256, 256, 0, stream>>>(ybuf, 4864, 2176, d2, BATCH, 2176);
        n = BATCH * 256;
        copyb_kernel<<<(n + 255) / 256, 256, 0, stream>>>(ybuf, 4864, 4352, cvec, BATCH, 256);
        copyb_kernel<<<(n + 255) / 256, 256, 0, stream>>>(ybuf, 4864, 4608, pvec, BATCH, 256);
    }
    launch_gemm_sk(ybuf, WT_f1, bf1, y1, part, BATCH, 512, 4864, 8, ACT_RELU, stream);
    launch_gemm_sk(y1, WT_f2, bf2, y2, part, BATCH, 256, 512, 4, ACT_RELU, stream);
    final_kernel<<<BATCH, 256, 0, stream>>>(y2, Wout, bout, outp);
}

// Round 4
// 1258.120 us; speedup vs baseline: 3.8156x; 1.1714x over previous
//
#include <hip/hip_runtime.h>
#include <math.h>

// ---------------------------------------------------------------------------
// Model dims (fixed by the reference)
// ---------------------------------------------------------------------------
#define BATCH   1024
#define NPG     32
#define NNODES  (BATCH * NPG)      // 32768 per drug
#define EPG     128
#define INFEAT  78
#define CCH     128
#define NHEAD   8
#define GENE    18000
#define GENEP   18016              // padded to %32
#define PROT    6688
#define FPD     2048

#define ACT_NONE 0
#define ACT_RELU 1
#define ACT_ELU  2

typedef unsigned short ushort_t;
typedef __bf16 bf16x8_t __attribute__((ext_vector_type(8)));
typedef float  f32x4_t  __attribute__((ext_vector_type(4)));

__device__ __forceinline__ float b2f(ushort_t u) {
    return __uint_as_float(((unsigned)u) << 16);
}
__device__ __forceinline__ ushort_t f2b(float f) {
    unsigned x = __float_as_uint(f);
    return (ushort_t)((x + 0x7fffu + ((x >> 16) & 1u)) >> 16);   // RNE
}

// ---------------------------------------------------------------------------
// bf16 MFMA GEMM (m97 structure): C[M,N] = act(A[M,K] @ BT[N,K]^T + bias)
// A, BT bf16 (K%32==0); C bf16; bias fp32. M%128==0, N%128==0.
// 128x128 tile, BK=32, 256 threads (2x2 waves of 64x64), global_load_lds.
// ---------------------------------------------------------------------------
#define GBM 128
#define GBN 128
#define GBK 32

__device__ __forceinline__ void gemm_core(
    const ushort_t* __restrict__ A, const ushort_t* __restrict__ BT,
    int K, int kb, int ke, int row0, int col0,
    ushort_t* Asl, ushort_t* Bsl, f32x4_t acc[4][4])
{
    const int tid  = threadIdx.x;
    const int wave = tid >> 6;
    const int lane = tid & 63;
    const int wr   = wave >> 1;
    const int wc   = wave & 1;
    const int srow = lane >> 2;        // 0..15
    const int skel = (lane & 3) * 8;   // bf16 elem offset

    for (int k0 = kb; k0 < ke; k0 += GBK) {
        __syncthreads();               // protect LDS from previous iteration
        #pragma unroll
        for (int t = 0; t < 2; ++t) {
            const int rg = wave * 32 + t * 16;                   // wave-uniform
            const ushort_t* ga = A + (size_t)(row0 + rg + srow) * K + k0 + skel;
            __builtin_amdgcn_global_load_lds(
                (const __attribute__((address_space(1))) void*)ga,
                (__attribute__((address_space(3))) void*)&Asl[rg * GBK], 16, 0, 0);
            const ushort_t* gb = BT + (size_t)(col0 + rg + srow) * K + k0 + skel;
            __builtin_amdgcn_global_load_lds(
                (const __attribute__((address_space(1))) void*)gb,
                (__attribute__((address_space(3))) void*)&Bsl[rg * GBK], 16, 0, 0);
        }
        __syncthreads();

        const int fr = lane & 15;
        const int fq = lane >> 4;
        bf16x8_t av[4], bv[4];
        #pragma unroll
        for (int i = 0; i < 4; ++i)
            av[i] = *(const bf16x8_t*)&Asl[(wr * 64 + i * 16 + fr) * GBK + fq * 8];
        #pragma unroll
        for (int j = 0; j < 4; ++j)
            bv[j] = *(const bf16x8_t*)&Bsl[(wc * 64 + j * 16 + fr) * GBK + fq * 8];
        #pragma unroll
        for (int i = 0; i < 4; ++i)
            #pragma unroll
            for (int j = 0; j < 4; ++j)
                acc[i][j] = __builtin_amdgcn_mfma_f32_16x16x32_bf16(
                    av[i], bv[j], acc[i][j], 0, 0, 0);
    }
}

__global__ __launch_bounds__(256) void gemm_bf16_kernel(
    const ushort_t* __restrict__ A, const ushort_t* __restrict__ BT,
    const float* __restrict__ bias, ushort_t* __restrict__ C,
    int M, int N, int K, int act)
{
    __shared__ ushort_t Asl[GBM * GBK];
    __shared__ ushort_t Bsl[GBN * GBK];
    const int lane = threadIdx.x & 63;
    const int wave = threadIdx.x >> 6;
    const int wr = wave >> 1, wc = wave & 1;
    const int row0 = blockIdx.y * GBM;
    const int col0 = blockIdx.x * GBN;

    f32x4_t acc[4][4] = {};
    gemm_core(A, BT, K, 0, K, row0, col0, Asl, Bsl, acc);

    const int fr = lane & 15;
    const int fq = lane >> 4;
    #pragma unroll
    for (int i = 0; i < 4; ++i) {
        #pragma unroll
        for (int j = 0; j < 4; ++j) {
            const int gn = col0 + wc * 64 + j * 16 + fr;
            const float bb = bias ? bias[gn] : 0.0f;
            #pragma unroll
            for (int r = 0; r < 4; ++r) {
                const int gm = row0 + wr * 64 + i * 16 + fq * 4 + r;
                float v = acc[i][j][r] + bb;
                if (act == ACT_RELU)     v = fmaxf(v, 0.0f);
                else if (act == ACT_ELU) v = (v > 0.0f) ? v : (expf(v) - 1.0f);
                C[(size_t)gm * N + gn] = f2b(v);
            }
        }
    }
}

// split-K variant: grid.z = chunk index, fp32 partials out (no bias/act)
__global__ __launch_bounds__(256) void gemm_bf16_part_kernel(
    const ushort_t* __restrict__ A, const ushort_t* __restrict__ BT,
    float* __restrict__ part, int M, int N, int K, int KC)
{
    __shared__ ushort_t Asl[GBM * GBK];
    __shared__ ushort_t Bsl[GBN * GBK];
    const int lane = threadIdx.x & 63;
    const int wave = threadIdx.x >> 6;
    const int wr = wave >> 1, wc = wave & 1;
    const int row0 = blockIdx.y * GBM;
    const int col0 = blockIdx.x * GBN;
    const int z    = blockIdx.z;
    const int kb   = z * KC;
    const int ke   = min(K, kb + KC);

    f32x4_t acc[4][4] = {};
    gemm_core(A, BT, K, kb, ke, row0, col0, Asl, Bsl, acc);

    const int fr = lane & 15;
    const int fq = lane >> 4;
    float* po = part + (size_t)z * M * N;
    #pragma unroll
    for (int i = 0; i < 4; ++i)
        #pragma unroll
        for (int j = 0; j < 4; ++j) {
            const int gn = col0 + wc * 64 + j * 16 + fr;
            #pragma unroll
            for (int r = 0; r < 4; ++r) {
                const int gm = row0 + wr * 64 + i * 16 + fq * 4 + r;
                po[(size_t)gm * N + gn] = acc[i][j][r];
            }
        }
}

// sum S partials + bias + act -> bf16
__global__ __launch_bounds__(256) void reduce_kernel(
    const float* __restrict__ part, const float* __restrict__ bias,
    ushort_t* __restrict__ C, int MN, int N, int S, int act)
{
    int i4 = (blockIdx.x * 256 + threadIdx.x) * 4;
    if (i4 >= MN) return;
    float4 s = *(const float4*)&part[i4];
    for (int z = 1; z < S; ++z) {
        float4 v = *(const float4*)&part[(size_t)z * MN + i4];
        s.x += v.x; s.y += v.y; s.z += v.z; s.w += v.w;
    }
    const int n = i4 % N;
    float o[4] = { s.x, s.y, s.z, s.w };
    if (bias) { o[0] += bias[n]; o[1] += bias[n+1]; o[2] += bias[n+2]; o[3] += bias[n+3]; }
    unsigned pk[2];
    ushort_t r[4];
    #pragma unroll
    for (int k = 0; k < 4; ++k) {
        float v = o[k];
        if (act == ACT_RELU)     v = fmaxf(v, 0.0f);
        else if (act == ACT_ELU) v = (v > 0.0f) ? v : (expf(v) - 1.0f);
        r[k] = f2b(v);
    }
    pk[0] = (unsigned)r[0] | ((unsigned)r[1] << 16);
    pk[1] = (unsigned)r[2] | ((unsigned)r[3] << 16);
    *(uint2*)&C[i4] = make_uint2(pk[0], pk[1]);
}

// ---------------------------------------------------------------------------
// fp32 [R][Cin] (optional rowscale) -> bf16 [R][Cpad], zero-padded
// ---------------------------------------------------------------------------
__global__ __launch_bounds__(256) void cast_rows_kernel(
    const float* __restrict__ src, const float* __restrict__ rowscale,
    ushort_t* __restrict__ dst, int R, int Cin, int Cpad)
{
    int idx = blockIdx.x * 256 + threadIdx.x;
    if (idx >= R * Cpad) return;
    int r = idx / Cpad, c = idx - r * Cpad;
    float v = 0.0f;
    if (c < Cin) {
        v = src[(size_t)r * Cin + c];
        if (rowscale) v *= rowscale[r];
    }
    dst[idx] = f2b(v);
}

// ---------------------------------------------------------------------------
// fp32 W[K][N] -> bf16 WT[N][Kpad] (transpose + pad), 32x32 LDS tiles
// ---------------------------------------------------------------------------
__global__ __launch_bounds__(256) void castT_kernel(
    const float* __restrict__ W, ushort_t* __restrict__ WT,
    int K, int N, int Kpad)
{
    __shared__ float t[32][33];
    const int nb = blockIdx.x * 32, kb = blockIdx.y * 32;
    const int x = threadIdx.x & 31, y = threadIdx.x >> 5;   // 32 x 8
    #pragma unroll
    for (int yy = 0; yy < 32; yy += 8) {
        int k = kb + y + yy, n = nb + x;
        t[y + yy][x] = (k < K && n < N) ? W[(size_t)k * N + n] : 0.0f;
    }
    __syncthreads();
    #pragma unroll
    for (int yy = 0; yy < 32; yy += 8) {
        int n = nb + y + yy, kk = kb + x;
        if (n < N && kk < Kpad) WT[(size_t)n * Kpad + kk] = f2b(t[x][y + yy]);
    }
}

// ---------------------------------------------------------------------------
// monotone float<->uint encoding for atomicMax on floats
// ---------------------------------------------------------------------------
__device__ __forceinline__ unsigned enc_f(float f) {
    unsigned u = __float_as_uint(f);
    return (u >> 31) ? ~u : (u | 0x80000000u);
}
__device__ __forceinline__ float dec_f(unsigned e) {
    return (e >> 31) ? __uint_as_float(e ^ 0x80000000u) : __uint_as_float(~e);
}

// ---------------------------------------------------------------------------
// Fully fused GAT stage: attention logits + softmax + dense-A aggregation.
// One block (256 thr) per (graph, head). h bf16 [N][H*128].
//   a_s[n] = sum_c h[n][c]*a_src[c];  e = leaky(a_s[src]+a_d[dst])
//   alpha scattered into dense At[s][d];  out = elu(A @ h + bias)
// POOL=1 (GAT2): write only per-graph column max (global max pool fused).
// ---------------------------------------------------------------------------
template <int POOL>
__global__ __launch_bounds__(256) void gat_fused_kernel(
    const ushort_t* __restrict__ h, const int* __restrict__ esrc,
    const int* __restrict__ edst, const float* __restrict__ a_src,
    const float* __restrict__ a_dst, const float* __restrict__ bias,
    ushort_t* __restrict__ out, int H)
{
    const int g    = blockIdx.x / H;
    const int hd   = blockIdx.x % H;
    const int tid  = threadIdx.x;
    const int lane = tid & 63;
    const int wave = tid >> 6;
    const int base = g * NPG;
    const int HC   = H * CCH;

    __shared__ float h_l[NPG][CCH];          // 16 KB
    __shared__ float At[NPG][NPG];           // 4 KB, At[s][d]
    __shared__ float asv[CCH], adv[CCH];
    __shared__ float as_l[NPG], ad_l[NPG];
    __shared__ unsigned m_l[NPG];
    __shared__ float den_l[NPG];
    __shared__ float sc_l[EPG + NPG];
    __shared__ unsigned char s_l[EPG + NPG], d_l[EPG + NPG];
    __shared__ float ptmp[2][CCH];

    // ---- load h slice (bf16 pairs), zero At, load a-vectors ----
    {
        const int r4 = tid >> 6;             // 0..3
        const int cp = (tid & 63) * 2;       // col pair
        #pragma unroll
        for (int rr = 0; rr < NPG; rr += 4) {
            const int r = rr + r4;
            unsigned v = *(const unsigned*)(h + (size_t)(base + r) * HC + hd * CCH + cp);
            h_l[r][cp]     = b2f((ushort_t)(v & 0xffff));
            h_l[r][cp + 1] = b2f((ushort_t)(v >> 16));
        }
    }
    #pragma unroll
    for (int i = tid; i < NPG * NPG; i += 256) ((float*)At)[i] = 0.0f;
    if (tid < CCH) asv[tid] = a_src[hd * CCH + tid];
    else           adv[tid - CCH] = a_dst[hd * CCH + tid - CCH];
    if (tid < NPG) { m_l[tid] = 0u; den_l[tid] = 0.0f; }
    __syncthreads();

    // ---- attention logits per node (wave-parallel, shuffle reduce) ----
    for (int n = wave; n < NPG; n += 4) {
        float v0 = h_l[n][lane], v1 = h_l[n][lane + 64];
        float s = v0 * asv[lane] + v1 * asv[lane + 64];
        float d = v0 * adv[lane] + v1 * adv[lane + 64];
        #pragma unroll
        for (int o = 32; o > 0; o >>= 1) {
            s += __shfl_xor(s, o, 64);
            d += __shfl_xor(d, o, 64);
        }
        if (lane == 0) { as_l[n] = s; ad_l[n] = d; }
    }
    __syncthreads();

    // ---- edge scores + segment max ----
    if (tid < EPG + NPG) {
        int s, d;
        if (tid < EPG) {
            s = esrc[g * EPG + tid] - base;
            d = edst[g * EPG + tid] - base;
        } else {
            s = d = tid - EPG;               // self-loop
        }
        float e = as_l[s] + ad_l[d];
        e = (e >= 0.0f) ? e : 0.2f * e;      // leaky_relu 0.2
        sc_l[tid] = e;
        s_l[tid] = (unsigned char)s;
        d_l[tid] = (unsigned char)d;
        atomicMax(&m_l[d], enc_f(e));
    }
    __syncthreads();

    // ---- exp + segment sum ----
    if (tid < EPG + NPG) {
        float ex = expf(sc_l[tid] - dec_f(m_l[d_l[tid]]));
        sc_l[tid] = ex;
        atomicAdd(&den_l[d_l[tid]], ex);
    }
    __syncthreads();

    // ---- scatter alpha into dense At[s][d] ----
    if (tid < EPG + NPG) {
        float al = sc_l[tid] / (den_l[d_l[tid]] + 1e-16f);
        atomicAdd(&At[s_l[tid]][d_l[tid]], al);
    }
    __syncthreads();

    // ---- out[d][c] = sum_s At[s][d] * h_l[s][c]  (register-tiled) ----
    const int c    = tid & 127;
    const int half = tid >> 7;               // d range half*16 .. +16
    float acc[16] = {};
    #pragma unroll 4
    for (int s = 0; s < NPG; ++s) {
        const float hv = h_l[s][c];
        const float4* ap = (const float4*)&At[s][half * 16];
        #pragma unroll
        for (int q = 0; q < 4; ++q) {
            float4 av = ap[q];               // wave-uniform broadcast
            acc[q * 4 + 0] += av.x * hv;
            acc[q * 4 + 1] += av.y * hv;
            acc[q * 4 + 2] += av.z * hv;
            acc[q * 4 + 3] += av.w * hv;
        }
    }

    const float bb = bias[hd * CCH + c];
    if (POOL) {
        float m = -INFINITY;
        #pragma unroll
        for (int r = 0; r < 16; ++r) {
            float v = acc[r] + bb;
            v = (v > 0.0f) ? v : (expf(v) - 1.0f);
            m = fmaxf(m, v);
        }
        ptmp[half][c] = m;
        __syncthreads();
        if (tid < CCH)
            out[(size_t)g * CCH + tid] = f2b(fmaxf(ptmp[0][tid], ptmp[1][tid]));
    } else {
        #pragma unroll
        for (int r = 0; r < 16; ++r) {
            float v = acc[r] + bb;
            v = (v > 0.0f) ? v : (expf(v) - 1.0f);
            out[(size_t)(base + half * 16 + r) * HC + hd * CCH + c] = f2b(v);
        }
    }
}

// ---------------------------------------------------------------------------
// Per-row inverse L2 norm (gene branch, fp32 input)
// ---------------------------------------------------------------------------
__global__ __launch_bounds__(256) void rownorm_kernel(
    const float* __restrict__ x, float* __restrict__ inv, int K)
{
    const int row = blockIdx.x;
    const int tid = threadIdx.x;
    const float* xp = x + (size_t)row * K;
    float s = 0.f;
    for (int k = tid; k < K; k += 256) { float v = xp[k]; s += v * v; }
    __shared__ float red[256];
    red[tid] = s;
    __syncthreads();
    for (int o = 128; o > 0; o >>= 1) {
        if (tid < o) red[tid] += red[tid + o];
        __syncthreads();
    }
    if (tid == 0) inv[row] = 1.0f / fmaxf(sqrtf(red[0]), 1e-12f);
}

// ---------------------------------------------------------------------------
// Column-block copy helpers (into concat buffers)
// ---------------------------------------------------------------------------
__global__ __launch_bounds__(256) void copyb_kernel(
    ushort_t* __restrict__ dst, int ld, int off,
    const ushort_t* __restrict__ src, int rows, int cols)
{
    int idx = blockIdx.x * 256 + threadIdx.x;
    if (idx >= rows * cols) return;
    int r = idx / cols, c = idx - r * cols;
    dst[(size_t)r * ld + off + c] = src[idx];
}

__global__ __launch_bounds__(256) void castcols_kernel(
    ushort_t* __restrict__ dst, int ld, int off,
    const float* __restrict__ src, int rows, int cols)
{
    int idx = blockIdx.x * 256 + threadIdx.x;
    if (idx >= rows * cols) return;
    int r = idx / cols, c = idx - r * cols;
    dst[(size_t)r * ld + off + c] = f2b(src[idx]);
}

// ---------------------------------------------------------------------------
// Final N_TASKS=1: out[b] = y[b,:256] . w + bout   (y bf16)
// ---------------------------------------------------------------------------
__global__ __launch_bounds__(256) void final_kernel(
    const ushort_t* __restrict__ y, const float* __restrict__ w,
    const float* __restrict__ b, float* __restrict__ out)
{
    const int row = blockIdx.x;
    const int tid = threadIdx.x;
    float v = b2f(y[(size_t)row * 256 + tid]) * w[tid];
    __shared__ float red[256];
    red[tid] = v;
    __syncthreads();
    for (int o = 128; o > 0; o >>= 1) {
        if (tid < o) red[tid] += red[tid + o];
        __syncthreads();
    }
    if (tid == 0) out[row] = red[0] + b[0];
}

// ---------------------------------------------------------------------------
// Host side
// ---------------------------------------------------------------------------
static inline void launch_gemm(const ushort_t* A, const ushort_t* BT,
                               const float* bias, ushort_t* C,
                               int M, int N, int K, int act, hipStream_t stream)
{
    dim3 grid(N / GBN, M / GBM);
    gemm_bf16_kernel<<<grid, 256, 0, stream>>>(A, BT, bias, C, M, N, K, act);
}

// split-K GEMM: partials into `part` (fp32), then reduce with bias+act
static inline void launch_gemm_sk(const ushort_t* A, const ushort_t* BT,
                                  const float* bias, ushort_t* C, float* part,
                                  int M, int N, int K, int S, int act,
                                  hipStream_t stream)
{
    if (S <= 1) { launch_gemm(A, BT, bias, C, M, N, K, act, stream); return; }
    const int iters = K / GBK;
    const int ipc   = (iters + S - 1) / S;         // iters per chunk
    const int S_eff = (iters + ipc - 1) / ipc;     // no empty chunks
    const int KC    = ipc * GBK;
    dim3 grid(N / GBN, M / GBM, S_eff);
    gemm_bf16_part_kernel<<<grid, 256, 0, stream>>>(A, BT, part, M, N, K, KC);
    const int MN = M * N;
    reduce_kernel<<<(MN / 4 + 255) / 256, 256, 0, stream>>>(
        part, bias, C, MN, N, S_eff, act);
}

static inline void launch_castT(const float* W, ushort_t* WT, int K, int N,
                                int Kpad, hipStream_t stream)
{
    dim3 grid((N + 31) / 32, (Kpad + 31) / 32);
    castT_kernel<<<grid, 256, 0, stream>>>(W, WT, K, N, Kpad);
}

extern "C" void kernel_launch(void* const* d_in, const int* in_sizes, int n_in,
                              void* d_out, int out_size, void* d_ws, size_t ws_size,
                              hipStream_t stream)
{
    const float* x1      = (const float*)d_in[0];
    const float* x2      = (const float*)d_in[1];
    const float* gene    = (const float*)d_in[2];
    const float* drr     = (const float*)d_in[3];
    const float* drc     = (const float*)d_in[4];
    const float* prot    = (const float*)d_in[5];
    const int*   ei1     = (const int*)d_in[6];
    const int*   ei2     = (const int*)d_in[7];
    const float* W_gat1  = (const float*)d_in[9];
    const float* b_gat1  = (const float*)d_in[10];
    const float* a_src1  = (const float*)d_in[11];
    const float* a_dst1  = (const float*)d_in[12];
    const float* W_gat2  = (const float*)d_in[13];
    const float* b_gat2  = (const float*)d_in[14];
    const float* a_src2  = (const float*)d_in[15];
    const float* a_dst2  = (const float*)d_in[16];
    const float* W_fcg   = (const float*)d_in[17];
    const float* b_fcg   = (const float*)d_in[18];
    const float* Wr1     = (const float*)d_in[19];
    const float* br1     = (const float*)d_in[20];
    const float* Wr2     = (const float*)d_in[21];
    const float* br2     = (const float*)d_in[22];
    const float* Wr3     = (const float*)d_in[23];
    const float* br3     = (const float*)d_in[24];
    const float* Wp1     = (const float*)d_in[25];
    const float* bp1     = (const float*)d_in[26];
    const float* Wp2     = (const float*)d_in[27];
    const float* bp2     = (const float*)d_in[28];
    const float* Wp3     = (const float*)d_in[29];
    const float* bp3     = (const float*)d_in[30];
    const float* Wdrr    = (const float*)d_in[31];
    const float* bdrr    = (const float*)d_in[32];
    const float* Wdrc    = (const float*)d_in[33];
    const float* bdrc    = (const float*)d_in[34];
    const float* Wf1     = (const float*)d_in[35];
    const float* bf1     = (const float*)d_in[36];
    const float* Wf2     = (const float*)d_in[37];
    const float* bf2     = (const float*)d_in[38];
    const float* Wout    = (const float*)d_in[39];
    const float* bout    = (const float*)d_in[40];
    float* outp = (float*)d_out;

    char* ws = (char*)d_ws;
    size_t off = 0;
    auto alloc = [&](size_t bytes) -> char* {
        char* r = ws + off;
        off += (bytes + 255) & ~(size_t)255;
        return r;
    };

    // Phase-overlaid big regions:
    // BIG0 (134 MB): drug phase = go1_full [65536x1024 bf16]
    //                MLP phase  = WT_r1 + gene_nb + cell1 + WT_r2 + WT_p2 + WT_p1
    // BIG1 (67 MB):  drug phase = h1 [32768x1024 bf16] (per-drug, reused)
    //                MLP phase  = split-K fp32 partial buffer (max 67 MB, gene S=8)
    char* BIG0 = alloc(134217728);
    char* BIG1 = alloc(67108864);

    ushort_t* go1f   = (ushort_t*)BIG0;
    ushort_t* h1     = (ushort_t*)BIG1;
    float*    part   = (float*)BIG1;
    ushort_t* WT_r1  = (ushort_t*)(BIG0 + 0);           // 2048x18016 = 73,793,536
    ushort_t* gene_nb= (ushort_t*)(BIG0 + 73793536);    // 1024x18016 = 36,896,768
    ushort_t* cell1  = (ushort_t*)(BIG0 + 110690304);   // 1024x2048  =  4,194,304
    ushort_t* WT_r2  = (ushort_t*)(BIG0 + 114884608);   // 512x2048   =  2,097,152
    ushort_t* WT_p2  = (ushort_t*)(BIG0 + 116981760);   // 512x1024   =  1,048,576
    ushort_t* WT_p1  = (ushort_t*)(BIG0 + 118030336);   // 1024x6688  = 13,697,024 -> 131,727,360

    ushort_t* xb     = (ushort_t*)alloc((size_t)NNODES * 96 * 2);        // per-drug
    char*     h2reg  = alloc((size_t)2 * NNODES * 128 * 2);              // 16.8 MB
    char*     catreg = alloc((size_t)2 * 1024 * 2176 * 2);               //  8.9 MB
    ushort_t* h2f    = (ushort_t*)h2reg;     // drug phase
    ushort_t* protb  = (ushort_t*)h2reg;     // MLP phase alias (13.7 MB <= 16.8)
    ushort_t* cat1   = (ushort_t*)catreg;
    ushort_t* cat2   = (ushort_t*)(catreg + (size_t)1024 * 2176 * 2);
    ushort_t* pooled = (ushort_t*)alloc((size_t)2 * BATCH * 128 * 2);
    ushort_t* gpair  = (ushort_t*)alloc((size_t)2 * BATCH * 128 * 2);
    float*    invn   = (float*)alloc((size_t)BATCH * 4);
    ushort_t* cvec   = (ushort_t*)alloc((size_t)BATCH * 256 * 2);
    ushort_t* pvec   = (ushort_t*)alloc((size_t)BATCH * 256 * 2);
    ushort_t* y1     = (ushort_t*)alloc((size_t)BATCH * 512 * 2);
    ushort_t* y2     = (ushort_t*)alloc((size_t)BATCH * 256 * 2);
    ushort_t* WT_g1  = (ushort_t*)alloc((size_t)1024 * 96 * 2);
    ushort_t* WT_g2  = (ushort_t*)alloc((size_t)128 * 1024 * 2);
    ushort_t* WT_fcg = (ushort_t*)alloc((size_t)128 * 128 * 2);
    ushort_t* WT_r3  = (ushort_t*)alloc((size_t)256 * 512 * 2);
    ushort_t* WT_p3  = (ushort_t*)alloc((size_t)256 * 512 * 2);
    ushort_t* WT_f2  = (ushort_t*)alloc((size_t)256 * 512 * 2);
    ushort_t* WT_drr = (ushort_t*)alloc((size_t)2176 * 2176 * 2);
    ushort_t* WT_drc = (ushort_t*)alloc((size_t)2176 * 2176 * 2);
    ushort_t* WT_f1  = (ushort_t*)alloc((size_t)512 * 4864 * 2);
    ushort_t* p1b    = (ushort_t*)alloc((size_t)1024 * 1024 * 2);
    ushort_t* p2b    = (ushort_t*)alloc((size_t)1024 * 512 * 2);
    ushort_t* cell2  = (ushort_t*)alloc((size_t)1024 * 512 * 2);
    ushort_t* d1     = (ushort_t*)alloc((size_t)1024 * 2176 * 2);
    ushort_t* d2     = (ushort_t*)alloc((size_t)1024 * 2176 * 2);
    ushort_t* ybuf   = (ushort_t*)alloc((size_t)1024 * 4864 * 2);

    const int E = in_sizes[6] / 2;   // 131072

    // ---------------- drug-phase weight casts ----------------
    launch_castT(W_gat1, WT_g1, INFEAT, 1024, 96, stream);
    launch_castT(W_gat2, WT_g2, 1024, 128, 1024, stream);
    launch_castT(W_fcg,  WT_fcg, 128, 128, 128, stream);

    // ---------------- drug branch: GAT1 per drug, write into shared go1f ---
    for (int drug = 0; drug < 2; drug++) {
        const float* x  = drug ? x2 : x1;
        const int*   es = (drug ? ei2 : ei1);
        const int*   ed = es + E;
        ushort_t* go1d = go1f + (size_t)drug * NNODES * 1024;

        cast_rows_kernel<<<(NNODES * 96 + 255) / 256, 256, 0, stream>>>(
            x, nullptr, xb, NNODES, INFEAT, 96);
        launch_gemm(xb, WT_g1, nullptr, h1, NNODES, 1024, 96, ACT_NONE, stream);
        gat_fused_kernel<0><<<BATCH * NHEAD, 256, 0, stream>>>(
            h1, es, ed, a_src1, a_dst1, b_gat1, go1d, NHEAD);
    }

    // ---------------- batched GAT2 GEMM (M=65536 -> 512 blocks) ------------
    launch_gemm(go1f, WT_g2, nullptr, h2f, 2 * NNODES, 128, 1024, ACT_NONE, stream);

    // BIG0 (go1f) now dead -> cast MLP-phase weights into it
    launch_castT(Wr1, WT_r1, GENE, 2048, GENEP, stream);
    launch_castT(Wr2, WT_r2, 2048, 512, 2048, stream);
    launch_castT(Wp1, WT_p1, PROT, 1024, PROT, stream);
    launch_castT(Wp2, WT_p2, 1024, 512, 1024, stream);
    launch_castT(Wr3, WT_r3, 512, 256, 512, stream);
    launch_castT(Wp3, WT_p3, 512, 256, 512, stream);
    launch_castT(Wf2, WT_f2, 512, 256, 512, stream);
    launch_castT(Wdrr, WT_drr, 2176, 2176, 2176, stream);
    launch_castT(Wdrc, WT_drc, 2176, 2176, 2176, stream);
    launch_castT(Wf1, WT_f1, 4864, 512, 4864, stream);

    // ---------------- GAT2 fused (attn + softmax + agg + maxpool) ----------
    for (int drug = 0; drug < 2; drug++) {
        const int* es = (drug ? ei2 : ei1);
        const int* ed = es + E;
        gat_fused_kernel<1><<<BATCH, 256, 0, stream>>>(
            h2f + (size_t)drug * NNODES * 128, es, ed,
            a_src2, a_dst2, b_gat2, pooled + (size_t)drug * BATCH * 128, 1);
    }
    launch_gemm(pooled, WT_fcg, b_fcg, gpair, 2 * BATCH, 128, 128, ACT_RELU, stream);
    // gpair rows [0,1024) = g1, [1024,2048) = g2

    // ---------------- gene branch (split-K) ----------------
    rownorm_kernel<<<BATCH, 256, 0, stream>>>(gene, invn, GENE);
    cast_rows_kernel<<<(BATCH * GENEP + 255) / 256, 256, 0, stream>>>(
        gene, invn, gene_nb, BATCH, GENE, GENEP);
    launch_gemm_sk(gene_nb, WT_r1, br1, cell1, part, BATCH, 2048, GENEP, 8, ACT_RELU, stream);
    launch_gemm_sk(cell1, WT_r2, br2, cell2, part, BATCH, 512, 2048, 8, ACT_RELU, stream);
    launch_gemm_sk(cell2, WT_r3, br3, cvec, part, BATCH, 256, 512, 4, ACT_RELU, stream);

    // ---------------- protein branch (split-K; protb aliases dead h2f) -----
    cast_rows_kernel<<<(BATCH * PROT + 255) / 256, 256, 0, stream>>>(
        prot, nullptr, protb, BATCH, PROT, PROT);
    launch_gemm_sk(protb, WT_p1, bp1, p1b, part, BATCH, 1024, PROT, 8, ACT_ELU, stream);
    launch_gemm_sk(p1b, WT_p2, bp2, p2b, part, BATCH, 512, 1024, 4, ACT_ELU, stream);
    launch_gemm_sk(p2b, WT_p3, bp3, pvec, part, BATCH, 256, 512, 4, ACT_RELU, stream);

    // ---------------- fingerprint fusion ----------------
    {
        int n = BATCH * CCH;
        copyb_kernel<<<(n + 255) / 256, 256, 0, stream>>>(cat1, 2176, 0, gpair, BATCH, CCH);
        copyb_kernel<<<(n + 255) / 256, 256, 0, stream>>>(cat2, 2176, 0, gpair + BATCH * CCH, BATCH, CCH);
        n = BATCH * FPD;
        castcols_kernel<<<(n + 255) / 256, 256, 0, stream>>>(cat1, 2176, CCH, drr, BATCH, FPD);
        castcols_kernel<<<(n + 255) / 256, 256, 0, stream>>>(cat2, 2176, CCH, drc, BATCH, FPD);
    }
    launch_gemm_sk(cat1, WT_drr, bdrr, d1, part, BATCH, 2176, 2176, 4, ACT_RELU, stream);
    launch_gemm_sk(cat2, WT_drc, bdrc, d2, part, BATCH, 2176, 2176, 4, ACT_RELU, stream);

    // ---------------- concat + predictor ----------------
    {
        int n = BATCH * 2176;
        copyb_kernel<<<(n + 255) / 256, 256, 0, stream>>>(ybuf, 4864, 0,    d1, BATCH, 2176);
        copyb_kernel<<<(n + 255) / 256, 256, 0, stream>>>(ybuf, 4864, 2176, d2, BATCH, 2176);
        n = BATCH * 256;
        copyb_kernel<<<(n + 255) / 256, 256, 0, stream>>>(ybuf, 4864, 4352, cvec, BATCH, 256);
        copyb_kernel<<<(n + 255) / 256, 256, 0, stream>>>(ybuf, 4864, 4608, pvec, BATCH, 256);
    }
    launch_gemm_sk(ybuf, WT_f1, bf1, y1, part, BATCH, 512, 4864, 8, ACT_RELU, stream);
    launch_gemm_sk(y1, WT_f2, bf2, y2, part, BATCH, 256, 512, 4, ACT_RELU, stream);
    final_kernel<<<BATCH, 256, 0, stream>>>(y2, Wout, bout, outp);
}